// Round 1
// baseline (478.874 us; speedup 1.0000x reference)
//
#include <hip/hip_runtime.h>
#include <hip/hip_bf16.h>
#include <cstdint>

// ---------- types ----------
typedef __attribute__((ext_vector_type(8))) short short8;     // 8 x bf16 raw
typedef __attribute__((ext_vector_type(4))) float floatx4;
typedef __attribute__((ext_vector_type(4))) unsigned short ushort4v;

// ---------- helpers ----------
__device__ __forceinline__ float bf2f(unsigned short u) {
    union { unsigned int u; float f; } v;
    v.u = ((unsigned int)u) << 16;
    return v.f;
}
__device__ __forceinline__ unsigned short f2bf(float f) {
    union { float f; unsigned int u; } v; v.f = f;
    unsigned int u = v.u;
    unsigned int r = (u + 0x7FFFu + ((u >> 16) & 1u)) >> 16;  // RNE
    return (unsigned short)r;
}
__device__ __forceinline__ void gld_lds16(const void* g, void* l) {
    __builtin_amdgcn_global_load_lds(
        (const __attribute__((address_space(1))) unsigned int*)g,
        (__attribute__((address_space(3))) unsigned int*)l,
        16, 0, 0);
}

// ---------- f32 -> bf16 convert (vectorized) ----------
__global__ __launch_bounds__(256) void cvt_bf16_kernel(const float* __restrict__ in,
                                                       unsigned short* __restrict__ out,
                                                       int n4) {
    int i = blockIdx.x * 256 + threadIdx.x;
    if (i >= n4) return;
    float4 v = ((const float4*)in)[i];
    ushort4v o;
    o.x = f2bf(v.x); o.y = f2bf(v.y); o.z = f2bf(v.z); o.w = f2bf(v.w);
    ((ushort4v*)out)[i] = o;
}

// ---------- weight transpose + convert: in [K][N] f32 -> out [N][K] bf16 ----------
__global__ __launch_bounds__(256) void transpose_cvt_kernel(const float* __restrict__ in,
                                                            unsigned short* __restrict__ out,
                                                            int K, int N) {
    __shared__ float tile[32][33];
    const int n0 = blockIdx.x * 32;
    const int k0 = blockIdx.y * 32;
    const int tx = threadIdx.x;   // 0..31
    const int ty = threadIdx.y;   // 0..7
#pragma unroll
    for (int i = 0; i < 32; i += 8)
        tile[ty + i][tx] = in[(size_t)(k0 + ty + i) * N + n0 + tx];
    __syncthreads();
#pragma unroll
    for (int i = 0; i < 32; i += 8)
        out[(size_t)(n0 + ty + i) * K + k0 + tx] = f2bf(tile[tx][ty + i]);
}

// ---------- bf16 GEMM: C[M][N] = A[M][K] * Bt[N][K]^T (+bias) ----------
// 128x128 tile, BK=32, 4 waves (2x2), 16x16x32 MFMA, global_load_lds staging.
template <bool OUT_BF16, bool HAS_BIAS>
__global__ __launch_bounds__(256, 2)
void gemm_bt(const unsigned short* __restrict__ A, const unsigned short* __restrict__ Bt,
             void* __restrict__ Cv, const float* __restrict__ bias,
             int M, int N, int K, int ldc) {
    __shared__ alignas(16) unsigned short As[128 * 32];
    __shared__ alignas(16) unsigned short Bs[128 * 32];

    const int tid  = threadIdx.x;
    const int lane = tid & 63;
    const int wave = tid >> 6;
    const int blockM = blockIdx.y * 128;
    const int blockN = blockIdx.x * 128;
    const int wm = wave >> 1, wn = wave & 1;

    // staging: chunk ci = r*256 + tid; row = ci>>2 (0..127), k-chunk = (ci&3)*8
    const int rA0 = tid >> 2;              // rows 0..63 (round 0); +64 round 1
    const int cc8 = (tid & 3) * 8;
    const unsigned short* gA0 = A  + (size_t)(blockM + rA0) * K + cc8;
    const unsigned short* gA1 = A  + (size_t)(blockM + 64 + rA0) * K + cc8;
    const unsigned short* gB0 = Bt + (size_t)(blockN + rA0) * K + cc8;
    const unsigned short* gB1 = Bt + (size_t)(blockN + 64 + rA0) * K + cc8;
    unsigned short* lA0 = &As[wave * 512];          // wave-uniform base, lane*16B auto
    unsigned short* lA1 = &As[2048 + wave * 512];
    unsigned short* lB0 = &Bs[wave * 512];
    unsigned short* lB1 = &Bs[2048 + wave * 512];

    floatx4 acc[4][4];
#pragma unroll
    for (int i = 0; i < 4; i++)
#pragma unroll
        for (int j = 0; j < 4; j++) acc[i][j] = (floatx4){0.f, 0.f, 0.f, 0.f};

    const int col  = lane & 15;
    const int quad = lane >> 4;
    const int aoff = (wm * 64 + col) * 32 + quad * 8;
    const int boff = (wn * 64 + col) * 32 + quad * 8;

    const int kIters = K >> 5;
    for (int kt = 0; kt < kIters; ++kt) {
        const size_t ko = (size_t)kt * 32;
        gld_lds16(gA0 + ko, lA0);
        gld_lds16(gA1 + ko, lA1);
        gld_lds16(gB0 + ko, lB0);
        gld_lds16(gB1 + ko, lB1);
        __syncthreads();   // drains vmcnt before LDS reads

        short8 a[4], b[4];
#pragma unroll
        for (int i = 0; i < 4; i++) a[i] = *(const short8*)&As[aoff + i * 16 * 32];
#pragma unroll
        for (int j = 0; j < 4; j++) b[j] = *(const short8*)&Bs[boff + j * 16 * 32];
#pragma unroll
        for (int i = 0; i < 4; i++)
#pragma unroll
            for (int j = 0; j < 4; j++)
                acc[i][j] = __builtin_amdgcn_mfma_f32_16x16x32_bf16(a[i], b[j], acc[i][j], 0, 0, 0);
        __syncthreads();   // protect LDS before next staging
    }

    // epilogue: C/D layout col=lane&15, row=quad*4+reg
#pragma unroll
    for (int i = 0; i < 4; i++) {
#pragma unroll
        for (int j = 0; j < 4; j++) {
#pragma unroll
            for (int r = 0; r < 4; r++) {
                int row = blockM + wm * 64 + i * 16 + quad * 4 + r;
                int cn  = blockN + wn * 64 + j * 16 + col;
                float v = acc[i][j][r];
                if (HAS_BIAS) v += bias[cn];
                if (OUT_BF16) ((unsigned short*)Cv)[(size_t)row * ldc + cn] = f2bf(v);
                else          ((float*)Cv)[(size_t)row * ldc + cn] = v;
            }
        }
    }
}

// ---------- attention: one wave per (b, h), 2x2 scores ----------
__global__ __launch_bounds__(256) void attn_kernel(const unsigned short* __restrict__ qkv,
                                                   unsigned short* __restrict__ attn_out) {
    const int gw   = (blockIdx.x * 256 + threadIdx.x) >> 6;
    const int lane = threadIdx.x & 63;
    const int b = gw >> 4;
    const int h = gw & 15;
    const size_t r0 = (size_t)(2 * b) * 3072 + h * 64 + lane;
    const size_t r1 = r0 + 3072;
    float q0 = bf2f(qkv[r0]),        q1 = bf2f(qkv[r1]);
    float k0 = bf2f(qkv[r0 + 1024]), k1 = bf2f(qkv[r1 + 1024]);
    float v0 = bf2f(qkv[r0 + 2048]), v1 = bf2f(qkv[r1 + 2048]);
    float s00 = q0 * k0, s01 = q0 * k1, s10 = q1 * k0, s11 = q1 * k1;
#pragma unroll
    for (int off = 32; off > 0; off >>= 1) {
        s00 += __shfl_xor(s00, off);
        s01 += __shfl_xor(s01, off);
        s10 += __shfl_xor(s10, off);
        s11 += __shfl_xor(s11, off);
    }
    const float sc = 0.125f;  // (1024/16)^-0.5
    s00 *= sc; s01 *= sc; s10 *= sc; s11 *= sc;
    float m0 = fmaxf(s00, s01), m1 = fmaxf(s10, s11);
    float e00 = __expf(s00 - m0), e01 = __expf(s01 - m0);
    float e10 = __expf(s10 - m1), e11 = __expf(s11 - m1);
    float o0 = (e00 * v0 + e01 * v1) / (e00 + e01);
    float o1 = (e10 * v0 + e11 * v1) / (e10 + e11);
    const size_t w0 = (size_t)(2 * b) * 1024 + h * 64 + lane;
    attn_out[w0]        = f2bf(o0);
    attn_out[w0 + 1024] = f2bf(o1);
}

// ---------- LayerNorm(2048) + residual ----------
__global__ __launch_bounds__(256) void ln_res_kernel(const float* __restrict__ proj,
                                                     const unsigned short* __restrict__ xres,
                                                     const float* __restrict__ gamma,
                                                     const float* __restrict__ beta,
                                                     float* __restrict__ out) {
    const int b = blockIdx.x;
    const int tid = threadIdx.x;
    const size_t base = (size_t)b * 2048;
    const float4* p = (const float4*)(proj + base);
    float4 v0 = p[tid];
    float4 v1 = p[256 + tid];
    float s  = v0.x + v0.y + v0.z + v0.w + v1.x + v1.y + v1.z + v1.w;
    float ss = v0.x*v0.x + v0.y*v0.y + v0.z*v0.z + v0.w*v0.w
             + v1.x*v1.x + v1.y*v1.y + v1.z*v1.z + v1.w*v1.w;
#pragma unroll
    for (int off = 32; off > 0; off >>= 1) {
        s  += __shfl_xor(s, off);
        ss += __shfl_xor(ss, off);
    }
    __shared__ float red[8];
    const int wave = tid >> 6;
    if ((tid & 63) == 0) { red[wave] = s; red[4 + wave] = ss; }
    __syncthreads();
    s  = red[0] + red[1] + red[2] + red[3];
    ss = red[4] + red[5] + red[6] + red[7];
    const float mean = s * (1.0f / 2048.0f);
    const float var  = ss * (1.0f / 2048.0f) - mean * mean;
    const float rstd = rsqrtf(var + 1e-5f);

    const float4* g  = (const float4*)gamma;
    const float4* be = (const float4*)beta;
    float4 g0 = g[tid], g1 = g[256 + tid];
    float4 b0 = be[tid], b1v = be[256 + tid];
    const ushort4v* xr = (const ushort4v*)(xres + base);
    ushort4v r0 = xr[tid], r1 = xr[256 + tid];
    float4 o0, o1;
    o0.x = (v0.x - mean) * rstd * g0.x + b0.x  + bf2f(r0.x);
    o0.y = (v0.y - mean) * rstd * g0.y + b0.y  + bf2f(r0.y);
    o0.z = (v0.z - mean) * rstd * g0.z + b0.z  + bf2f(r0.z);
    o0.w = (v0.w - mean) * rstd * g0.w + b0.w  + bf2f(r0.w);
    o1.x = (v1.x - mean) * rstd * g1.x + b1v.x + bf2f(r1.x);
    o1.y = (v1.y - mean) * rstd * g1.y + b1v.y + bf2f(r1.y);
    o1.z = (v1.z - mean) * rstd * g1.z + b1v.z + bf2f(r1.z);
    o1.w = (v1.w - mean) * rstd * g1.w + b1v.w + bf2f(r1.w);
    float4* op = (float4*)(out + base);
    op[tid] = o0;
    op[256 + tid] = o1;
}

// ---------- launch ----------
extern "C" void kernel_launch(void* const* d_in, const int* in_sizes, int n_in,
                              void* d_out, int out_size, void* d_ws, size_t ws_size,
                              hipStream_t stream) {
    (void)in_sizes; (void)n_in; (void)out_size; (void)ws_size;
    const float* features1 = (const float*)d_in[0];
    const float* features2 = (const float*)d_in[1];
    const float* W1   = (const float*)d_in[2];
    const float* b1   = (const float*)d_in[3];
    const float* W2   = (const float*)d_in[4];
    const float* b2   = (const float*)d_in[5];
    const float* Wqkv = (const float*)d_in[6];
    const float* Wout = (const float*)d_in[7];
    const float* bout = (const float*)d_in[8];
    const float* gamma = (const float*)d_in[9];
    const float* beta  = (const float*)d_in[10];
    float* out = (float*)d_out;

    // sizes: B=8192, IMG=2048, Q=768, H=1024
    char* ws = (char*)d_ws;
    unsigned short* f1b   = (unsigned short*)(ws);                 // 32 MiB
    unsigned short* f2b   = (unsigned short*)(ws + 33554432);      // 12 MiB
    unsigned short* W1t   = (unsigned short*)(ws + 46137344);      // 4 MiB   [1024][2048]
    unsigned short* W2t   = (unsigned short*)(ws + 50331648);      // 1.5 MiB [1024][768]
    unsigned short* Wqkvt = (unsigned short*)(ws + 51904512);      // 6 MiB   [3072][1024]
    unsigned short* Woutt = (unsigned short*)(ws + 58195968);      // 2 MiB   [1024][1024]
    unsigned short* xb    = (unsigned short*)(ws + 60293120);      // 32 MiB  [16384][1024]
    unsigned short* qkv   = (unsigned short*)(ws + 93847552);      // 96 MiB  [16384][3072]
    unsigned short* attn  = (unsigned short*)(ws + 194510848);     // 32 MiB  [16384][1024]
    float*          proj  = (float*)(ws + 93847552);               // 64 MiB, aliases qkv (dead)

    // 1) convert features to bf16
    cvt_bf16_kernel<<<16384, 256, 0, stream>>>(features1, f1b, 8192 * 2048 / 4);
    cvt_bf16_kernel<<<6144, 256, 0, stream>>>(features2, f2b, 8192 * 768 / 4);

    // 2) transpose + convert weights: W [K][N] -> Wt [N][K]
    transpose_cvt_kernel<<<dim3(1024 / 32, 2048 / 32), dim3(32, 8), 0, stream>>>(W1, W1t, 2048, 1024);
    transpose_cvt_kernel<<<dim3(1024 / 32, 768 / 32),  dim3(32, 8), 0, stream>>>(W2, W2t, 768, 1024);
    transpose_cvt_kernel<<<dim3(3072 / 32, 1024 / 32), dim3(32, 8), 0, stream>>>(Wqkv, Wqkvt, 1024, 3072);
    transpose_cvt_kernel<<<dim3(1024 / 32, 1024 / 32), dim3(32, 8), 0, stream>>>(Wout, Woutt, 1024, 1024);

    // 3) f1 = features1 @ W1 + b1  -> x rows even (ldc 2048)
    gemm_bt<true, true><<<dim3(1024 / 128, 8192 / 128), 256, 0, stream>>>(
        f1b, W1t, (void*)xb, b1, 8192, 1024, 2048, 2048);
    // 4) f2 = features2 @ W2 + b2  -> x rows odd
    gemm_bt<true, true><<<dim3(1024 / 128, 8192 / 128), 256, 0, stream>>>(
        f2b, W2t, (void*)(xb + 1024), b2, 8192, 1024, 768, 2048);
    // 5) qkv = x @ Wqkv  [16384][3072]
    gemm_bt<true, false><<<dim3(3072 / 128, 16384 / 128), 256, 0, stream>>>(
        xb, Wqkvt, (void*)qkv, nullptr, 16384, 3072, 1024, 3072);
    // 6) attention (2x2 per head)
    attn_kernel<<<8192 * 16 / 4, 256, 0, stream>>>(qkv, attn);
    // 7) proj = attn @ Wout + bout  [16384][1024] f32
    gemm_bt<false, true><<<dim3(1024 / 128, 16384 / 128), 256, 0, stream>>>(
        attn, Woutt, (void*)proj, bout, 16384, 1024, 1024, 1024);
    // 8) LayerNorm + residual
    ln_res_kernel<<<8192, 256, 0, stream>>>(proj, xb, gamma, beta, out);
}

// Round 2
// 405.148 us; speedup vs baseline: 1.1820x; 1.1820x over previous
//
#include <hip/hip_runtime.h>
#include <hip/hip_bf16.h>
#include <cstdint>

// ---------- types ----------
typedef __attribute__((ext_vector_type(8))) short short8;     // 8 x bf16 raw
typedef __attribute__((ext_vector_type(4))) short short4v;    // 4 x bf16 raw
typedef __attribute__((ext_vector_type(4))) float floatx4;
typedef __attribute__((ext_vector_type(4))) unsigned short ushort4v;

// ---------- helpers ----------
__device__ __forceinline__ float bf2f(unsigned short u) {
    union { unsigned int u; float f; } v;
    v.u = ((unsigned int)u) << 16;
    return v.f;
}
__device__ __forceinline__ unsigned short f2bf(float f) {
    union { float f; unsigned int u; } v; v.f = f;
    unsigned int u = v.u;
    unsigned int r = (u + 0x7FFFu + ((u >> 16) & 1u)) >> 16;  // RNE
    return (unsigned short)r;
}
__device__ __forceinline__ float lo_bf(unsigned int u) {
    union { unsigned int u; float f; } v; v.u = u << 16; return v.f;
}
__device__ __forceinline__ float hi_bf(unsigned int u) {
    union { unsigned int u; float f; } v; v.u = u & 0xffff0000u; return v.f;
}
__device__ __forceinline__ void gld_lds16(const void* g, void* l) {
    __builtin_amdgcn_global_load_lds(
        (const __attribute__((address_space(1))) unsigned int*)g,
        (__attribute__((address_space(3))) unsigned int*)l,
        16, 0, 0);
}

// ---------- f32 -> bf16 convert (vectorized) ----------
__global__ __launch_bounds__(256) void cvt_bf16_kernel(const float* __restrict__ in,
                                                       unsigned short* __restrict__ out,
                                                       int n4) {
    int i = blockIdx.x * 256 + threadIdx.x;
    if (i >= n4) return;
    float4 v = ((const float4*)in)[i];
    ushort4v o;
    o.x = f2bf(v.x); o.y = f2bf(v.y); o.z = f2bf(v.z); o.w = f2bf(v.w);
    ((ushort4v*)out)[i] = o;
}

// ---------- weight transpose + convert: in [K][N] f32 -> out [N][K] bf16 ----------
__global__ __launch_bounds__(256) void transpose_cvt_kernel(const float* __restrict__ in,
                                                            unsigned short* __restrict__ out,
                                                            int K, int N) {
    __shared__ float tile[32][33];
    const int n0 = blockIdx.x * 32;
    const int k0 = blockIdx.y * 32;
    const int tx = threadIdx.x;   // 0..31
    const int ty = threadIdx.y;   // 0..7
#pragma unroll
    for (int i = 0; i < 32; i += 8)
        tile[ty + i][tx] = in[(size_t)(k0 + ty + i) * N + n0 + tx];
    __syncthreads();
#pragma unroll
    for (int i = 0; i < 32; i += 8)
        out[(size_t)(n0 + ty + i) * K + k0 + tx] = f2bf(tile[tx][ty + i]);
}

// ---------- bf16 GEMM, BK=64 (two 32-K halves): C[M][N] = A[M][K]*Bt[N][K]^T (+bias) ----------
template <bool OUT_BF16, bool HAS_BIAS>
__global__ __launch_bounds__(256, 2)
void gemm_bt64(const unsigned short* __restrict__ A, const unsigned short* __restrict__ Bt,
               void* __restrict__ Cv, const float* __restrict__ bias,
               int M, int N, int K, int ldc) {
    __shared__ alignas(16) unsigned short As[8192];  // 2 halves x [128][32]
    __shared__ alignas(16) unsigned short Bs[8192];

    const int tid  = threadIdx.x;
    const int lane = tid & 63;
    const int wave = tid >> 6;
    const int blockM = blockIdx.y * 128;
    const int blockN = blockIdx.x * 128;
    const int wm = wave >> 1, wn = wave & 1;

    // staging: chunk ci = g*256+tid in [0,1024); LDS elem offset = ci*8
    // half hh = ci>>9, rem = ci&511, row = rem>>2, sub = rem&3
    const unsigned short* gA[4];
    const unsigned short* gB[4];
    unsigned short* lA[4];
    unsigned short* lB[4];
#pragma unroll
    for (int g = 0; g < 4; g++) {
        int ci = g * 256 + tid;
        int hh = ci >> 9, rem = ci & 511, row = rem >> 2, sub = rem & 3;
        gA[g] = A  + (size_t)(blockM + row) * K + hh * 32 + sub * 8;
        gB[g] = Bt + (size_t)(blockN + row) * K + hh * 32 + sub * 8;
        lA[g] = As + g * 2048 + wave * 512;   // wave-uniform base; lane*16B implicit
        lB[g] = Bs + g * 2048 + wave * 512;
    }

    floatx4 acc[4][4];
#pragma unroll
    for (int i = 0; i < 4; i++)
#pragma unroll
        for (int j = 0; j < 4; j++) acc[i][j] = (floatx4){0.f, 0.f, 0.f, 0.f};

    const int col  = lane & 15;
    const int quad = lane >> 4;
    const int aoff32 = (wm * 64 + col) * 32 + quad * 8;
    const int boff32 = (wn * 64 + col) * 32 + quad * 8;

    const int kIters = K >> 6;
    for (int kt = 0; kt < kIters; ++kt) {
        const size_t ko = (size_t)kt * 64;
#pragma unroll
        for (int g = 0; g < 4; g++) gld_lds16(gA[g] + ko, lA[g]);
#pragma unroll
        for (int g = 0; g < 4; g++) gld_lds16(gB[g] + ko, lB[g]);
        __syncthreads();

#pragma unroll
        for (int hh = 0; hh < 2; hh++) {
            short8 a[4], b[4];
#pragma unroll
            for (int i = 0; i < 4; i++) a[i] = *(const short8*)&As[hh * 4096 + aoff32 + i * 512];
#pragma unroll
            for (int j = 0; j < 4; j++) b[j] = *(const short8*)&Bs[hh * 4096 + boff32 + j * 512];
#pragma unroll
            for (int i = 0; i < 4; i++)
#pragma unroll
                for (int j = 0; j < 4; j++)
                    acc[i][j] = __builtin_amdgcn_mfma_f32_16x16x32_bf16(a[i], b[j], acc[i][j], 0, 0, 0);
        }
        __syncthreads();
    }

    // epilogue: C/D layout col=lane&15, row=quad*4+reg
#pragma unroll
    for (int i = 0; i < 4; i++) {
#pragma unroll
        for (int j = 0; j < 4; j++) {
#pragma unroll
            for (int r = 0; r < 4; r++) {
                int row = blockM + wm * 64 + i * 16 + quad * 4 + r;
                int cn  = blockN + wn * 64 + j * 16 + col;
                float v = acc[i][j][r];
                if (HAS_BIAS) v += bias[cn];
                if (OUT_BF16) ((unsigned short*)Cv)[(size_t)row * ldc + cn] = f2bf(v);
                else          ((float*)Cv)[(size_t)row * ldc + cn] = v;
            }
        }
    }
}

// ---------- fused qkv GEMM + 2x2 attention ----------
// Block = (head h, M-tile of 128 rows = 64 batch entries). Tile N=192 = q|k|v 64-col slices.
// A = x [16384][1024]; Bt = Wqkvt [3072][1024] (rows: q 0..1023, k 1024.., v 2048..).
// Writes attn_out [16384][1024] bf16 directly; qkv never hits HBM.
#define T2_STRIDE 132   // [c][r] transposed tile, c<192, r<128; stride%4==0 for b64 stores
__global__ __launch_bounds__(256, 2)
void gemm_qkv_attn(const unsigned short* __restrict__ A, const unsigned short* __restrict__ Bt,
                   unsigned short* __restrict__ attn_out) {
    __shared__ alignas(16) char smem[52224];
    unsigned short* As = (unsigned short*)smem;        // 8192 elems (16 KiB): 2 halves x [128][32]
    unsigned short* Bs = As + 8192;                    // 12288 elems (24 KiB): 2 halves x [192][32]
    unsigned short* T2 = (unsigned short*)smem;        // 192*132 = 25344 elems (50688 B), reuses staging
    float* wsm = (float*)(smem + 50688);               // 64*4 softmax weights

    const int tid  = threadIdx.x;
    const int lane = tid & 63;
    const int wave = tid >> 6;
    const int h = blockIdx.x;                 // head 0..15
    const int blockM = blockIdx.y * 128;
    const int wm = wave >> 1, wn = wave & 1;  // wave tile 64x96
    const int K = 1024;

    const unsigned short* gA[4];
    unsigned short* lA[4];
#pragma unroll
    for (int g = 0; g < 4; g++) {
        int ci = g * 256 + tid;
        int hh = ci >> 9, rem = ci & 511, row = rem >> 2, sub = rem & 3;
        gA[g] = A + (size_t)(blockM + row) * K + hh * 32 + sub * 8;
        lA[g] = As + g * 2048 + wave * 512;
    }
    const unsigned short* gB[6];
    unsigned short* lB[6];
#pragma unroll
    for (int g = 0; g < 6; g++) {
        int ci = g * 256 + tid;                    // [0,1536)
        int hh = (ci >= 768) ? 1 : 0;
        int rem = ci - hh * 768;
        int row = rem >> 2, sub = rem & 3;         // row in [0,192)
        int sec = row >> 6, wr = row & 63;         // q/k/v section
        gB[g] = Bt + (size_t)(sec * 1024 + h * 64 + wr) * K + hh * 32 + sub * 8;
        lB[g] = Bs + g * 2048 + wave * 512;
    }

    floatx4 acc[4][6];
#pragma unroll
    for (int i = 0; i < 4; i++)
#pragma unroll
        for (int j = 0; j < 6; j++) acc[i][j] = (floatx4){0.f, 0.f, 0.f, 0.f};

    const int col  = lane & 15;
    const int quad = lane >> 4;
    const int aoff32 = (wm * 64 + col) * 32 + quad * 8;
    const int boff32 = (wn * 96 + col) * 32 + quad * 8;

    for (int kt = 0; kt < 16; ++kt) {
        const size_t ko = (size_t)kt * 64;
#pragma unroll
        for (int g = 0; g < 4; g++) gld_lds16(gA[g] + ko, lA[g]);
#pragma unroll
        for (int g = 0; g < 6; g++) gld_lds16(gB[g] + ko, lB[g]);
        __syncthreads();

#pragma unroll
        for (int hh = 0; hh < 2; hh++) {
            short8 a[4], b[6];
#pragma unroll
            for (int i = 0; i < 4; i++) a[i] = *(const short8*)&As[hh * 4096 + aoff32 + i * 512];
#pragma unroll
            for (int j = 0; j < 6; j++) b[j] = *(const short8*)&Bs[hh * 6144 + boff32 + j * 512];
#pragma unroll
            for (int i = 0; i < 4; i++)
#pragma unroll
                for (int j = 0; j < 6; j++)
                    acc[i][j] = __builtin_amdgcn_mfma_f32_16x16x32_bf16(a[i], b[j], acc[i][j], 0, 0, 0);
        }
        __syncthreads();
    }
    // last barrier above: all LDS reads done; safe to overwrite staging with T2.

    // 1) store tile transposed: T2[c][r], c = feature (0..63 q | 64..127 k | 128..191 v), r = M-row
#pragma unroll
    for (int i = 0; i < 4; i++) {
#pragma unroll
        for (int j = 0; j < 6; j++) {
            int c  = wn * 96 + j * 16 + col;
            int r0 = wm * 64 + i * 16 + quad * 4;
            short4v pk;
            pk.x = (short)f2bf(acc[i][j][0]);
            pk.y = (short)f2bf(acc[i][j][1]);
            pk.z = (short)f2bf(acc[i][j][2]);
            pk.w = (short)f2bf(acc[i][j][3]);
            *(short4v*)&T2[c * T2_STRIDE + r0] = pk;
        }
    }
    __syncthreads();

    // 2) scores + softmax: thread ib (<64) handles batch-row pair (2ib, 2ib+1)
    if (tid < 64) {
        const int ib = tid;
        float s00 = 0.f, s01 = 0.f, s10 = 0.f, s11 = 0.f;
#pragma unroll 8
        for (int d = 0; d < 64; d++) {
            unsigned int qp = *(const unsigned int*)&T2[d * T2_STRIDE + 2 * ib];
            unsigned int kp = *(const unsigned int*)&T2[(64 + d) * T2_STRIDE + 2 * ib];
            float q0 = lo_bf(qp), q1 = hi_bf(qp);
            float k0 = lo_bf(kp), k1 = hi_bf(kp);
            s00 += q0 * k0; s01 += q0 * k1;
            s10 += q1 * k0; s11 += q1 * k1;
        }
        const float sc = 0.125f;   // (1024/16)^-0.5
        s00 *= sc; s01 *= sc; s10 *= sc; s11 *= sc;
        float m0 = fmaxf(s00, s01), m1 = fmaxf(s10, s11);
        float e00 = __expf(s00 - m0), e01 = __expf(s01 - m0);
        float e10 = __expf(s10 - m1), e11 = __expf(s11 - m1);
        float i0 = 1.f / (e00 + e01), i1 = 1.f / (e10 + e11);
        wsm[ib * 4 + 0] = e00 * i0; wsm[ib * 4 + 1] = e01 * i0;
        wsm[ib * 4 + 2] = e10 * i1; wsm[ib * 4 + 3] = e11 * i1;
    }
    __syncthreads();

    // 3) out = attn @ v, write global (128 rows x 64 cols = 1024 8-elem chunks)
#pragma unroll
    for (int g = 0; g < 4; g++) {
        int chunk = g * 256 + tid;
        int r = chunk >> 3;
        int dc = (chunk & 7) * 8;
        int ib = r >> 1, n = r & 1;
        float w0 = wsm[ib * 4 + n * 2 + 0];
        float w1 = wsm[ib * 4 + n * 2 + 1];
        short8 o;
#pragma unroll
        for (int dd = 0; dd < 8; dd++) {
            unsigned int vp = *(const unsigned int*)&T2[(128 + dc + dd) * T2_STRIDE + 2 * ib];
            o[dd] = (short)f2bf(w0 * lo_bf(vp) + w1 * hi_bf(vp));
        }
        *(short8*)&attn_out[(size_t)(blockM + r) * 1024 + h * 64 + dc] = o;
    }
}

// ---------- LayerNorm(2048) + residual; proj now bf16 ----------
__global__ __launch_bounds__(256) void ln_res_kernel(const unsigned short* __restrict__ proj,
                                                     const unsigned short* __restrict__ xres,
                                                     const float* __restrict__ gamma,
                                                     const float* __restrict__ beta,
                                                     float* __restrict__ out) {
    const int b = blockIdx.x;
    const int tid = threadIdx.x;
    const size_t base = (size_t)b * 2048;
    short8 p8 = ((const short8*)(proj + base))[tid];
    float pv[8];
#pragma unroll
    for (int e = 0; e < 8; e++) pv[e] = bf2f((unsigned short)p8[e]);
    float s = 0.f, ss = 0.f;
#pragma unroll
    for (int e = 0; e < 8; e++) { s += pv[e]; ss += pv[e] * pv[e]; }
#pragma unroll
    for (int off = 32; off > 0; off >>= 1) {
        s  += __shfl_xor(s, off);
        ss += __shfl_xor(ss, off);
    }
    __shared__ float red[8];
    const int wave = tid >> 6;
    if ((tid & 63) == 0) { red[wave] = s; red[4 + wave] = ss; }
    __syncthreads();
    s  = red[0] + red[1] + red[2] + red[3];
    ss = red[4] + red[5] + red[6] + red[7];
    const float mean = s * (1.0f / 2048.0f);
    const float var  = ss * (1.0f / 2048.0f) - mean * mean;
    const float rstd = rsqrtf(var + 1e-5f);

    const float4* g4 = (const float4*)gamma;
    const float4* b4 = (const float4*)beta;
    float4 g0 = g4[2 * tid], g1 = g4[2 * tid + 1];
    float4 be0 = b4[2 * tid], be1 = b4[2 * tid + 1];
    short8 r8 = ((const short8*)(xres + base))[tid];
    float4 o0, o1;
    o0.x = (pv[0] - mean) * rstd * g0.x + be0.x + bf2f((unsigned short)r8[0]);
    o0.y = (pv[1] - mean) * rstd * g0.y + be0.y + bf2f((unsigned short)r8[1]);
    o0.z = (pv[2] - mean) * rstd * g0.z + be0.z + bf2f((unsigned short)r8[2]);
    o0.w = (pv[3] - mean) * rstd * g0.w + be0.w + bf2f((unsigned short)r8[3]);
    o1.x = (pv[4] - mean) * rstd * g1.x + be1.x + bf2f((unsigned short)r8[4]);
    o1.y = (pv[5] - mean) * rstd * g1.y + be1.y + bf2f((unsigned short)r8[5]);
    o1.z = (pv[6] - mean) * rstd * g1.z + be1.z + bf2f((unsigned short)r8[6]);
    o1.w = (pv[7] - mean) * rstd * g1.w + be1.w + bf2f((unsigned short)r8[7]);
    float4* op = (float4*)(out + base);
    op[2 * tid] = o0;
    op[2 * tid + 1] = o1;
}

// ---------- launch ----------
extern "C" void kernel_launch(void* const* d_in, const int* in_sizes, int n_in,
                              void* d_out, int out_size, void* d_ws, size_t ws_size,
                              hipStream_t stream) {
    (void)in_sizes; (void)n_in; (void)out_size; (void)ws_size;
    const float* features1 = (const float*)d_in[0];
    const float* features2 = (const float*)d_in[1];
    const float* W1   = (const float*)d_in[2];
    const float* b1   = (const float*)d_in[3];
    const float* W2   = (const float*)d_in[4];
    const float* b2   = (const float*)d_in[5];
    const float* Wqkv = (const float*)d_in[6];
    const float* Wout = (const float*)d_in[7];
    const float* bout = (const float*)d_in[8];
    const float* gamma = (const float*)d_in[9];
    const float* beta  = (const float*)d_in[10];
    float* out = (float*)d_out;

    // B=8192, IMG=2048, Q=768, H=1024
    char* ws = (char*)d_ws;
    unsigned short* f1b   = (unsigned short*)(ws);                 // 32 MiB
    unsigned short* f2b   = (unsigned short*)(ws + 33554432);      // 12 MiB
    unsigned short* W1t   = (unsigned short*)(ws + 46137344);      // 4 MiB   [1024][2048]
    unsigned short* W2t   = (unsigned short*)(ws + 50331648);      // 1.5 MiB [1024][768]
    unsigned short* Wqkvt = (unsigned short*)(ws + 51904512);      // 6 MiB   [3072][1024]
    unsigned short* Woutt = (unsigned short*)(ws + 58195968);      // 2 MiB   [1024][1024]
    unsigned short* xb    = (unsigned short*)(ws + 60293120);      // 32 MiB  [16384][1024] (= [8192][2048])
    unsigned short* attn  = (unsigned short*)(ws + 93847552);      // 32 MiB  [16384][1024]
    unsigned short* projb = (unsigned short*)(ws + 127401984);     // 32 MiB  [16384][1024] bf16

    // 1) convert features to bf16
    cvt_bf16_kernel<<<16384, 256, 0, stream>>>(features1, f1b, 8192 * 2048 / 4);
    cvt_bf16_kernel<<<6144, 256, 0, stream>>>(features2, f2b, 8192 * 768 / 4);

    // 2) transpose + convert weights: W [K][N] -> Wt [N][K]
    transpose_cvt_kernel<<<dim3(1024 / 32, 2048 / 32), dim3(32, 8), 0, stream>>>(W1, W1t, 2048, 1024);
    transpose_cvt_kernel<<<dim3(1024 / 32, 768 / 32),  dim3(32, 8), 0, stream>>>(W2, W2t, 768, 1024);
    transpose_cvt_kernel<<<dim3(3072 / 32, 1024 / 32), dim3(32, 8), 0, stream>>>(Wqkv, Wqkvt, 1024, 3072);
    transpose_cvt_kernel<<<dim3(1024 / 32, 1024 / 32), dim3(32, 8), 0, stream>>>(Wout, Woutt, 1024, 1024);

    // 3) f1 = features1 @ W1 + b1  -> x rows even (ldc 2048)
    gemm_bt64<true, true><<<dim3(8, 64), 256, 0, stream>>>(
        f1b, W1t, (void*)xb, b1, 8192, 1024, 2048, 2048);
    // 4) f2 = features2 @ W2 + b2  -> x rows odd
    gemm_bt64<true, true><<<dim3(8, 64), 256, 0, stream>>>(
        f2b, W2t, (void*)(xb + 1024), b2, 8192, 1024, 768, 2048);
    // 5) fused qkv GEMM + attention -> attn [16384][1024] bf16 (qkv never materialized)
    gemm_qkv_attn<<<dim3(16, 128), 256, 0, stream>>>(xb, Wqkvt, attn);
    // 6) proj = attn @ Wout + bout -> bf16 [16384][1024]
    gemm_bt64<true, true><<<dim3(8, 128), 256, 0, stream>>>(
        attn, Woutt, (void*)projb, bout, 16384, 1024, 1024, 1024);
    // 7) LayerNorm + residual
    ln_res_kernel<<<8192, 256, 0, stream>>>(projb, xb, gamma, beta, out);
}

// Round 3
// 398.615 us; speedup vs baseline: 1.2013x; 1.0164x over previous
//
#include <hip/hip_runtime.h>
#include <hip/hip_bf16.h>
#include <cstdint>

// ---------- types ----------
typedef __attribute__((ext_vector_type(8))) short short8;     // 8 x bf16 raw
typedef __attribute__((ext_vector_type(4))) short short4v;    // 4 x bf16 raw
typedef __attribute__((ext_vector_type(4))) float floatx4;
typedef __attribute__((ext_vector_type(4))) unsigned short ushort4v;

// ---------- helpers ----------
__device__ __forceinline__ float bf2f(unsigned short u) {
    union { unsigned int u; float f; } v;
    v.u = ((unsigned int)u) << 16;
    return v.f;
}
__device__ __forceinline__ unsigned short f2bf(float f) {
    union { float f; unsigned int u; } v; v.f = f;
    unsigned int u = v.u;
    unsigned int r = (u + 0x7FFFu + ((u >> 16) & 1u)) >> 16;  // RNE
    return (unsigned short)r;
}
__device__ __forceinline__ float lo_bf(unsigned int u) {
    union { unsigned int u; float f; } v; v.u = u << 16; return v.f;
}
__device__ __forceinline__ float hi_bf(unsigned int u) {
    union { unsigned int u; float f; } v; v.u = u & 0xffff0000u; return v.f;
}
__device__ __forceinline__ void gld_lds16(const void* g, void* l) {
    __builtin_amdgcn_global_load_lds(
        (const __attribute__((address_space(1))) unsigned int*)g,
        (__attribute__((address_space(3))) unsigned int*)l,
        16, 0, 0);
}

// ---------- unified prep: feature cvt + all weight transposes, ONE dispatch ----------
// blocks [0,4096)      : cvt features1 (4096*1024 float4)
// blocks [4096,5632)   : cvt features2 (1536*1024 float4)
// blocks [5632,7680)   : transpose W1   [2048][1024] -> [1024][2048]
// blocks [7680,8448)   : transpose W2   [768][1024]  -> [1024][768]
// blocks [8448,11520)  : transpose Wqkv [1024][3072] -> [3072][1024]
// blocks [11520,12544) : transpose Wout [1024][1024] -> [1024][1024]
__global__ __launch_bounds__(256) void prep_kernel(
    const float* __restrict__ f1, const float* __restrict__ f2,
    unsigned short* __restrict__ f1b, unsigned short* __restrict__ f2b,
    const float* __restrict__ W1, unsigned short* __restrict__ W1t,
    const float* __restrict__ W2, unsigned short* __restrict__ W2t,
    const float* __restrict__ Wqkv, unsigned short* __restrict__ Wqkvt,
    const float* __restrict__ Wout, unsigned short* __restrict__ Woutt) {
    __shared__ float tile[32][33];
    const int b = blockIdx.x;
    const int tid = threadIdx.x;

    if (b < 5632) {
        const float* in = (b < 4096) ? f1 : f2;
        unsigned short* outp = (b < 4096) ? f1b : f2b;
        int base = ((b < 4096) ? b : (b - 4096)) * 1024 + tid;
#pragma unroll
        for (int it = 0; it < 4; it++) {
            int i = base + it * 256;
            float4 v = ((const float4*)in)[i];
            ushort4v o;
            o.x = f2bf(v.x); o.y = f2bf(v.y); o.z = f2bf(v.z); o.w = f2bf(v.w);
            ((ushort4v*)outp)[i] = o;
        }
        return;
    }

    const float* in; unsigned short* outp; int K, N, t;
    if (b < 7680)       { in = W1;   outp = W1t;   K = 2048; N = 1024; t = b - 5632;  }
    else if (b < 8448)  { in = W2;   outp = W2t;   K = 768;  N = 1024; t = b - 7680;  }
    else if (b < 11520) { in = Wqkv; outp = Wqkvt; K = 1024; N = 3072; t = b - 8448;  }
    else                { in = Wout; outp = Woutt; K = 1024; N = 1024; t = b - 11520; }
    const int ntiles = N >> 5;
    const int n0 = (t % ntiles) * 32;
    const int k0 = (t / ntiles) * 32;
    const int tx = tid & 31, ty = tid >> 5;
#pragma unroll
    for (int i = 0; i < 32; i += 8)
        tile[ty + i][tx] = in[(size_t)(k0 + ty + i) * N + n0 + tx];
    __syncthreads();
#pragma unroll
    for (int i = 0; i < 32; i += 8)
        outp[(size_t)(n0 + ty + i) * K + k0 + tx] = f2bf(tile[tx][ty + i]);
}

// ---------- bf16 GEMM core, BK=64: C[M][N] = A[M][K]*Bt[N][K]^T (+bias) ----------
// Single base pointer + affine offsets for staging (saves ~16 VGPRs vs pointer arrays).
template <bool OUT_BF16, bool HAS_BIAS>
__device__ __forceinline__ void gemm_core(const unsigned short* __restrict__ A,
                                          const unsigned short* __restrict__ Bt,
                                          void* __restrict__ Cv, const float* __restrict__ bias,
                                          int K, int ldc,
                                          unsigned short* As, unsigned short* Bs) {
    const int tid  = threadIdx.x;
    const int lane = tid & 63;
    const int wave = tid >> 6;
    const int blockM = blockIdx.y * 128;
    const int blockN = blockIdx.x * 128;
    const int wm = wave >> 1, wn = wave & 1;

    const unsigned short* gA = A  + (size_t)(blockM + (tid >> 2)) * K + (tid & 3) * 8;
    const unsigned short* gB = Bt + (size_t)(blockN + (tid >> 2)) * K + (tid & 3) * 8;
    const size_t sK = (size_t)64 * K;          // +64 rows
    unsigned short* lA = As + wave * 512;      // wave-uniform; lane*16B implicit
    unsigned short* lB = Bs + wave * 512;

    floatx4 acc[4][4];
#pragma unroll
    for (int i = 0; i < 4; i++)
#pragma unroll
        for (int j = 0; j < 4; j++) acc[i][j] = (floatx4){0.f, 0.f, 0.f, 0.f};

    const int col  = lane & 15;
    const int quad = lane >> 4;
    const int aoff32 = (wm * 64 + col) * 32 + quad * 8;
    const int boff32 = (wn * 64 + col) * 32 + quad * 8;

    const int kIters = K >> 6;
    for (int kt = 0; kt < kIters; ++kt) {
        const size_t ko = (size_t)kt * 64;
        gld_lds16(gA + ko,           lA);          // half0 rows 0..63
        gld_lds16(gA + sK + ko,      lA + 2048);   // half0 rows 64..127
        gld_lds16(gA + 32 + ko,      lA + 4096);   // half1 rows 0..63
        gld_lds16(gA + sK + 32 + ko, lA + 6144);   // half1 rows 64..127
        gld_lds16(gB + ko,           lB);
        gld_lds16(gB + sK + ko,      lB + 2048);
        gld_lds16(gB + 32 + ko,      lB + 4096);
        gld_lds16(gB + sK + 32 + ko, lB + 6144);
        __syncthreads();

#pragma unroll
        for (int hh = 0; hh < 2; hh++) {
            short8 a[4], bf[4];
#pragma unroll
            for (int i = 0; i < 4; i++) a[i] = *(const short8*)&As[hh * 4096 + aoff32 + i * 512];
#pragma unroll
            for (int j = 0; j < 4; j++) bf[j] = *(const short8*)&Bs[hh * 4096 + boff32 + j * 512];
#pragma unroll
            for (int i = 0; i < 4; i++)
#pragma unroll
                for (int j = 0; j < 4; j++)
                    acc[i][j] = __builtin_amdgcn_mfma_f32_16x16x32_bf16(a[i], bf[j], acc[i][j], 0, 0, 0);
        }
        __syncthreads();
    }

    // epilogue: C/D layout col=lane&15, row=quad*4+reg
#pragma unroll
    for (int i = 0; i < 4; i++) {
#pragma unroll
        for (int j = 0; j < 4; j++) {
#pragma unroll
            for (int r = 0; r < 4; r++) {
                int row = blockM + wm * 64 + i * 16 + quad * 4 + r;
                int cn  = blockN + wn * 64 + j * 16 + col;
                float v = acc[i][j][r];
                if (HAS_BIAS) v += bias[cn];
                if (OUT_BF16) ((unsigned short*)Cv)[(size_t)row * ldc + cn] = f2bf(v);
                else          ((float*)Cv)[(size_t)row * ldc + cn] = v;
            }
        }
    }
}

// ---------- merged modality GEMMs: z=0 -> f1 (K=2048), z=1 -> f2 (K=768) ----------
__global__ __launch_bounds__(256, 4)
void gemm_f12(const unsigned short* __restrict__ f1b, const unsigned short* __restrict__ W1t,
              const float* __restrict__ b1,
              const unsigned short* __restrict__ f2b, const unsigned short* __restrict__ W2t,
              const float* __restrict__ b2, unsigned short* __restrict__ xb) {
    __shared__ alignas(16) unsigned short As[8192];
    __shared__ alignas(16) unsigned short Bs[8192];
    if (blockIdx.z == 0)
        gemm_core<true, true>(f1b, W1t, (void*)xb, b1, 2048, 2048, As, Bs);
    else
        gemm_core<true, true>(f2b, W2t, (void*)(xb + 1024), b2, 768, 2048, As, Bs);
}

// ---------- out-proj GEMM ----------
__global__ __launch_bounds__(256, 4)
void gemm_proj(const unsigned short* __restrict__ attn, const unsigned short* __restrict__ Woutt,
               const float* __restrict__ bout, unsigned short* __restrict__ projb) {
    __shared__ alignas(16) unsigned short As[8192];
    __shared__ alignas(16) unsigned short Bs[8192];
    gemm_core<true, true>(attn, Woutt, (void*)projb, bout, 1024, 1024, As, Bs);
}

// ---------- fused qkv GEMM + 2x2 attention ----------
// Block = (head h, M-tile of 128 rows = 64 batch entries). Tile N=192 = q|k|v 64-col slices.
#define T2_STRIDE 132
__global__ __launch_bounds__(256, 3)
void gemm_qkv_attn(const unsigned short* __restrict__ A, const unsigned short* __restrict__ Bt,
                   unsigned short* __restrict__ attn_out) {
    __shared__ alignas(16) char smem[52224];
    unsigned short* As = (unsigned short*)smem;        // 8192 elems: 2 halves x [128][32]
    unsigned short* Bs = As + 8192;                    // 12288 elems: 2 halves x [192][32]
    unsigned short* T2 = (unsigned short*)smem;        // 192*132 elems, reuses staging
    float* wsm = (float*)(smem + 50688);               // 64*4 softmax weights

    const int tid  = threadIdx.x;
    const int lane = tid & 63;
    const int wave = tid >> 6;
    const int h = blockIdx.x;                 // head 0..15
    const int blockM = blockIdx.y * 128;
    const int wm = wave >> 1, wn = wave & 1;  // wave tile 64x96
    const int K = 1024;

    // single-base staging addresses (affine offsets; keeps VGPR low for 3 waves/SIMD)
    const unsigned short* gA = A  + (size_t)(blockM + (tid >> 2)) * K + (tid & 3) * 8;
    const unsigned short* gB = Bt + (size_t)(h * 64 + (tid >> 2)) * K + (tid & 3) * 8;
    unsigned short* lA = As + wave * 512;
    unsigned short* lB = Bs + wave * 512;

    floatx4 acc[4][6];
#pragma unroll
    for (int i = 0; i < 4; i++)
#pragma unroll
        for (int j = 0; j < 6; j++) acc[i][j] = (floatx4){0.f, 0.f, 0.f, 0.f};

    const int col  = lane & 15;
    const int quad = lane >> 4;
    const int aoff32 = (wm * 64 + col) * 32 + quad * 8;
    const int boff32 = (wn * 96 + col) * 32 + quad * 8;

    for (int kt = 0; kt < 16; ++kt) {
        const size_t ko = (size_t)kt * 64;
        gld_lds16(gA + ko,               lA);          // A half0 rows 0..63
        gld_lds16(gA + 65536 + ko,       lA + 2048);   // A half0 rows 64..127 (+64*1024)
        gld_lds16(gA + 32 + ko,          lA + 4096);   // A half1 rows 0..63
        gld_lds16(gA + 65536 + 32 + ko,  lA + 6144);   // A half1 rows 64..127
        gld_lds16(gB + ko,               lB);          // q, half0
        gld_lds16(gB + 1048576 + ko,     lB + 2048);   // k, half0 (+1024*1024)
        gld_lds16(gB + 2097152 + ko,     lB + 4096);   // v, half0 (+2048*1024)
        gld_lds16(gB + 32 + ko,          lB + 6144);   // q, half1
        gld_lds16(gB + 1048576 + 32 + ko, lB + 8192);  // k, half1
        gld_lds16(gB + 2097152 + 32 + ko, lB + 10240); // v, half1
        __syncthreads();

#pragma unroll
        for (int hh = 0; hh < 2; hh++) {
            short8 a[4], bf[6];
#pragma unroll
            for (int i = 0; i < 4; i++) a[i] = *(const short8*)&As[hh * 4096 + aoff32 + i * 512];
#pragma unroll
            for (int j = 0; j < 6; j++) bf[j] = *(const short8*)&Bs[hh * 6144 + boff32 + j * 512];
#pragma unroll
            for (int i = 0; i < 4; i++)
#pragma unroll
                for (int j = 0; j < 6; j++)
                    acc[i][j] = __builtin_amdgcn_mfma_f32_16x16x32_bf16(a[i], bf[j], acc[i][j], 0, 0, 0);
        }
        __syncthreads();
    }

    // 1) store tile transposed: T2[c][r], c = feature (q|k|v), r = M-row
#pragma unroll
    for (int i = 0; i < 4; i++) {
#pragma unroll
        for (int j = 0; j < 6; j++) {
            int c  = wn * 96 + j * 16 + col;
            int r0 = wm * 64 + i * 16 + quad * 4;
            short4v pk;
            pk.x = (short)f2bf(acc[i][j][0]);
            pk.y = (short)f2bf(acc[i][j][1]);
            pk.z = (short)f2bf(acc[i][j][2]);
            pk.w = (short)f2bf(acc[i][j][3]);
            *(short4v*)&T2[c * T2_STRIDE + r0] = pk;
        }
    }
    __syncthreads();

    // 2) scores + softmax: thread ib (<64) handles batch-row pair (2ib, 2ib+1)
    if (tid < 64) {
        const int ib = tid;
        float s00 = 0.f, s01 = 0.f, s10 = 0.f, s11 = 0.f;
#pragma unroll 8
        for (int d = 0; d < 64; d++) {
            unsigned int qp = *(const unsigned int*)&T2[d * T2_STRIDE + 2 * ib];
            unsigned int kp = *(const unsigned int*)&T2[(64 + d) * T2_STRIDE + 2 * ib];
            float q0 = lo_bf(qp), q1 = hi_bf(qp);
            float k0 = lo_bf(kp), k1 = hi_bf(kp);
            s00 += q0 * k0; s01 += q0 * k1;
            s10 += q1 * k0; s11 += q1 * k1;
        }
        const float sc = 0.125f;   // (1024/16)^-0.5
        s00 *= sc; s01 *= sc; s10 *= sc; s11 *= sc;
        float m0 = fmaxf(s00, s01), m1 = fmaxf(s10, s11);
        float e00 = __expf(s00 - m0), e01 = __expf(s01 - m0);
        float e10 = __expf(s10 - m1), e11 = __expf(s11 - m1);
        float i0 = 1.f / (e00 + e01), i1 = 1.f / (e10 + e11);
        wsm[ib * 4 + 0] = e00 * i0; wsm[ib * 4 + 1] = e01 * i0;
        wsm[ib * 4 + 2] = e10 * i1; wsm[ib * 4 + 3] = e11 * i1;
    }
    __syncthreads();

    // 3) out = attn @ v, write global (128 rows x 64 cols = 1024 8-elem chunks)
#pragma unroll
    for (int g = 0; g < 4; g++) {
        int chunk = g * 256 + tid;
        int r = chunk >> 3;
        int dc = (chunk & 7) * 8;
        int ib = r >> 1, n = r & 1;
        float w0 = wsm[ib * 4 + n * 2 + 0];
        float w1 = wsm[ib * 4 + n * 2 + 1];
        short8 o;
#pragma unroll
        for (int dd = 0; dd < 8; dd++) {
            unsigned int vp = *(const unsigned int*)&T2[(128 + dc + dd) * T2_STRIDE + 2 * ib];
            o[dd] = (short)f2bf(w0 * lo_bf(vp) + w1 * hi_bf(vp));
        }
        *(short8*)&attn_out[(size_t)(blockM + r) * 1024 + h * 64 + dc] = o;
    }
}

// ---------- LayerNorm(2048) + residual ----------
__global__ __launch_bounds__(256) void ln_res_kernel(const unsigned short* __restrict__ proj,
                                                     const unsigned short* __restrict__ xres,
                                                     const float* __restrict__ gamma,
                                                     const float* __restrict__ beta,
                                                     float* __restrict__ out) {
    const int b = blockIdx.x;
    const int tid = threadIdx.x;
    const size_t base = (size_t)b * 2048;
    short8 p8 = ((const short8*)(proj + base))[tid];
    float pv[8];
#pragma unroll
    for (int e = 0; e < 8; e++) pv[e] = bf2f((unsigned short)p8[e]);
    float s = 0.f, ss = 0.f;
#pragma unroll
    for (int e = 0; e < 8; e++) { s += pv[e]; ss += pv[e] * pv[e]; }
#pragma unroll
    for (int off = 32; off > 0; off >>= 1) {
        s  += __shfl_xor(s, off);
        ss += __shfl_xor(ss, off);
    }
    __shared__ float red[8];
    const int wave = tid >> 6;
    if ((tid & 63) == 0) { red[wave] = s; red[4 + wave] = ss; }
    __syncthreads();
    s  = red[0] + red[1] + red[2] + red[3];
    ss = red[4] + red[5] + red[6] + red[7];
    const float mean = s * (1.0f / 2048.0f);
    const float var  = ss * (1.0f / 2048.0f) - mean * mean;
    const float rstd = rsqrtf(var + 1e-5f);

    const float4* g4 = (const float4*)gamma;
    const float4* b4 = (const float4*)beta;
    float4 g0 = g4[2 * tid], g1 = g4[2 * tid + 1];
    float4 be0 = b4[2 * tid], be1 = b4[2 * tid + 1];
    short8 r8 = ((const short8*)(xres + base))[tid];
    float4 o0, o1;
    o0.x = (pv[0] - mean) * rstd * g0.x + be0.x + bf2f((unsigned short)r8[0]);
    o0.y = (pv[1] - mean) * rstd * g0.y + be0.y + bf2f((unsigned short)r8[1]);
    o0.z = (pv[2] - mean) * rstd * g0.z + be0.z + bf2f((unsigned short)r8[2]);
    o0.w = (pv[3] - mean) * rstd * g0.w + be0.w + bf2f((unsigned short)r8[3]);
    o1.x = (pv[4] - mean) * rstd * g1.x + be1.x + bf2f((unsigned short)r8[4]);
    o1.y = (pv[5] - mean) * rstd * g1.y + be1.y + bf2f((unsigned short)r8[5]);
    o1.z = (pv[6] - mean) * rstd * g1.z + be1.z + bf2f((unsigned short)r8[6]);
    o1.w = (pv[7] - mean) * rstd * g1.w + be1.w + bf2f((unsigned short)r8[7]);
    float4* op = (float4*)(out + base);
    op[2 * tid] = o0;
    op[2 * tid + 1] = o1;
}

// ---------- launch ----------
extern "C" void kernel_launch(void* const* d_in, const int* in_sizes, int n_in,
                              void* d_out, int out_size, void* d_ws, size_t ws_size,
                              hipStream_t stream) {
    (void)in_sizes; (void)n_in; (void)out_size; (void)ws_size;
    const float* features1 = (const float*)d_in[0];
    const float* features2 = (const float*)d_in[1];
    const float* W1   = (const float*)d_in[2];
    const float* b1   = (const float*)d_in[3];
    const float* W2   = (const float*)d_in[4];
    const float* b2   = (const float*)d_in[5];
    const float* Wqkv = (const float*)d_in[6];
    const float* Wout = (const float*)d_in[7];
    const float* bout = (const float*)d_in[8];
    const float* gamma = (const float*)d_in[9];
    const float* beta  = (const float*)d_in[10];
    float* out = (float*)d_out;

    // B=8192, IMG=2048, Q=768, H=1024
    char* ws = (char*)d_ws;
    unsigned short* f1b   = (unsigned short*)(ws);                 // 32 MiB
    unsigned short* f2b   = (unsigned short*)(ws + 33554432);      // 12 MiB
    unsigned short* W1t   = (unsigned short*)(ws + 46137344);      // 4 MiB   [1024][2048]
    unsigned short* W2t   = (unsigned short*)(ws + 50331648);      // 1.5 MiB [1024][768]
    unsigned short* Wqkvt = (unsigned short*)(ws + 51904512);      // 6 MiB   [3072][1024]
    unsigned short* Woutt = (unsigned short*)(ws + 58195968);      // 2 MiB   [1024][1024]
    unsigned short* xb    = (unsigned short*)(ws + 60293120);      // 32 MiB  [16384][1024] (= [8192][2048])
    unsigned short* attn  = (unsigned short*)(ws + 93847552);      // 32 MiB  [16384][1024]
    unsigned short* projb = (unsigned short*)(ws + 127401984);     // 32 MiB  [16384][1024] bf16

    // 1) unified prep (feature cvt + weight transposes)
    prep_kernel<<<12544, 256, 0, stream>>>(features1, features2, f1b, f2b,
                                           W1, W1t, W2, W2t, Wqkv, Wqkvt, Wout, Woutt);
    // 2) f1/f2 modality GEMMs, one dispatch
    gemm_f12<<<dim3(8, 64, 2), 256, 0, stream>>>(f1b, W1t, b1, f2b, W2t, b2, xb);
    // 3) fused qkv GEMM + attention -> attn [16384][1024] bf16
    gemm_qkv_attn<<<dim3(16, 128), 256, 0, stream>>>(xb, Wqkvt, attn);
    // 4) proj = attn @ Wout + bout -> bf16
    gemm_proj<<<dim3(8, 128), 256, 0, stream>>>(attn, Woutt, bout, projb);
    // 5) LayerNorm + residual
    ln_res_kernel<<<8192, 256, 0, stream>>>(projb, xb, gamma, beta, out);
}

// Round 4
// 397.729 us; speedup vs baseline: 1.2040x; 1.0022x over previous
//
#include <hip/hip_runtime.h>
#include <hip/hip_bf16.h>
#include <cstdint>

// ---------- types ----------
typedef __attribute__((ext_vector_type(8))) short short8;     // 8 x bf16 raw
typedef __attribute__((ext_vector_type(4))) short short4v;    // 4 x bf16 raw
typedef __attribute__((ext_vector_type(4))) float floatx4;
typedef __attribute__((ext_vector_type(4))) unsigned short ushort4v;

// ---------- helpers ----------
__device__ __forceinline__ float bf2f(unsigned short u) {
    union { unsigned int u; float f; } v;
    v.u = ((unsigned int)u) << 16;
    return v.f;
}
__device__ __forceinline__ unsigned short f2bf(float f) {
    union { float f; unsigned int u; } v; v.f = f;
    unsigned int u = v.u;
    unsigned int r = (u + 0x7FFFu + ((u >> 16) & 1u)) >> 16;  // RNE
    return (unsigned short)r;
}
__device__ __forceinline__ float lo_bf(unsigned int u) {
    union { unsigned int u; float f; } v; v.u = u << 16; return v.f;
}
__device__ __forceinline__ float hi_bf(unsigned int u) {
    union { unsigned int u; float f; } v; v.u = u & 0xffff0000u; return v.f;
}
__device__ __forceinline__ void gld_lds16(const void* g, void* l) {
    __builtin_amdgcn_global_load_lds(
        (const __attribute__((address_space(1))) unsigned int*)g,
        (__attribute__((address_space(3))) unsigned int*)l,
        16, 0, 0);
}

// ---------- unified prep: feature cvt + all weight transposes, ONE dispatch ----------
__global__ __launch_bounds__(256) void prep_kernel(
    const float* __restrict__ f1, const float* __restrict__ f2,
    unsigned short* __restrict__ f1b, unsigned short* __restrict__ f2b,
    const float* __restrict__ W1, unsigned short* __restrict__ W1t,
    const float* __restrict__ W2, unsigned short* __restrict__ W2t,
    const float* __restrict__ Wqkv, unsigned short* __restrict__ Wqkvt,
    const float* __restrict__ Wout, unsigned short* __restrict__ Woutt) {
    __shared__ float tile[32][33];
    const int b = blockIdx.x;
    const int tid = threadIdx.x;

    if (b < 5632) {
        const float* in = (b < 4096) ? f1 : f2;
        unsigned short* outp = (b < 4096) ? f1b : f2b;
        int base = ((b < 4096) ? b : (b - 4096)) * 1024 + tid;
#pragma unroll
        for (int it = 0; it < 4; it++) {
            int i = base + it * 256;
            float4 v = ((const float4*)in)[i];
            ushort4v o;
            o.x = f2bf(v.x); o.y = f2bf(v.y); o.z = f2bf(v.z); o.w = f2bf(v.w);
            ((ushort4v*)outp)[i] = o;
        }
        return;
    }

    const float* in; unsigned short* outp; int K, N, t;
    if (b < 7680)       { in = W1;   outp = W1t;   K = 2048; N = 1024; t = b - 5632;  }
    else if (b < 8448)  { in = W2;   outp = W2t;   K = 768;  N = 1024; t = b - 7680;  }
    else if (b < 11520) { in = Wqkv; outp = Wqkvt; K = 1024; N = 3072; t = b - 8448;  }
    else                { in = Wout; outp = Woutt; K = 1024; N = 1024; t = b - 11520; }
    const int ntiles = N >> 5;
    const int n0 = (t % ntiles) * 32;
    const int k0 = (t / ntiles) * 32;
    const int tx = tid & 31, ty = tid >> 5;
#pragma unroll
    for (int i = 0; i < 32; i += 8)
        tile[ty + i][tx] = in[(size_t)(k0 + ty + i) * N + n0 + tx];
    __syncthreads();
#pragma unroll
    for (int i = 0; i < 32; i += 8)
        outp[(size_t)(n0 + ty + i) * K + k0 + tx] = f2bf(tile[tx][ty + i]);
}

// ---------- bf16 GEMM core, BK=64: C[M][N] = A[M][K]*Bt[N][K]^T (+bias) ----------
// b-fragment-outer inner loop: a[4] preloaded (16 VGPR), one b-frag live (4 VGPR)
// -> low arch-VGPR so acc(64 AGPR) + arch fits 3 waves/SIMD.
template <bool OUT_BF16, bool HAS_BIAS>
__device__ __forceinline__ void gemm_core(const unsigned short* __restrict__ A,
                                          const unsigned short* __restrict__ Bt,
                                          void* __restrict__ Cv, const float* __restrict__ bias,
                                          int K, int ldc,
                                          unsigned short* As, unsigned short* Bs) {
    const int tid  = threadIdx.x;
    const int lane = tid & 63;
    const int wave = tid >> 6;
    const int blockM = blockIdx.y * 128;
    const int blockN = blockIdx.x * 128;
    const int wm = wave >> 1, wn = wave & 1;

    const unsigned short* gA = A  + (size_t)(blockM + (tid >> 2)) * K + (tid & 3) * 8;
    const unsigned short* gB = Bt + (size_t)(blockN + (tid >> 2)) * K + (tid & 3) * 8;
    const size_t sK = (size_t)64 * K;          // +64 rows
    unsigned short* lA = As + wave * 512;      // wave-uniform; lane*16B implicit
    unsigned short* lB = Bs + wave * 512;

    floatx4 acc[4][4];
#pragma unroll
    for (int i = 0; i < 4; i++)
#pragma unroll
        for (int j = 0; j < 4; j++) acc[i][j] = (floatx4){0.f, 0.f, 0.f, 0.f};

    const int col  = lane & 15;
    const int quad = lane >> 4;
    const int aoff32 = (wm * 64 + col) * 32 + quad * 8;
    const int boff32 = (wn * 64 + col) * 32 + quad * 8;

    const int kIters = K >> 6;
    for (int kt = 0; kt < kIters; ++kt) {
        const size_t ko = (size_t)kt * 64;
        gld_lds16(gA + ko,           lA);
        gld_lds16(gA + sK + ko,      lA + 2048);
        gld_lds16(gA + 32 + ko,      lA + 4096);
        gld_lds16(gA + sK + 32 + ko, lA + 6144);
        gld_lds16(gB + ko,           lB);
        gld_lds16(gB + sK + ko,      lB + 2048);
        gld_lds16(gB + 32 + ko,      lB + 4096);
        gld_lds16(gB + sK + 32 + ko, lB + 6144);
        __syncthreads();

#pragma unroll
        for (int hh = 0; hh < 2; hh++) {
            short8 a[4];
#pragma unroll
            for (int i = 0; i < 4; i++) a[i] = *(const short8*)&As[hh * 4096 + aoff32 + i * 512];
#pragma unroll
            for (int j = 0; j < 4; j++) {
                short8 bj = *(const short8*)&Bs[hh * 4096 + boff32 + j * 512];
#pragma unroll
                for (int i = 0; i < 4; i++)
                    acc[i][j] = __builtin_amdgcn_mfma_f32_16x16x32_bf16(a[i], bj, acc[i][j], 0, 0, 0);
            }
        }
        __syncthreads();
    }

    // epilogue: C/D layout col=lane&15, row=quad*4+reg
#pragma unroll
    for (int i = 0; i < 4; i++) {
#pragma unroll
        for (int j = 0; j < 4; j++) {
#pragma unroll
            for (int r = 0; r < 4; r++) {
                int row = blockM + wm * 64 + i * 16 + quad * 4 + r;
                int cn  = blockN + wn * 64 + j * 16 + col;
                float v = acc[i][j][r];
                if (HAS_BIAS) v += bias[cn];
                if (OUT_BF16) ((unsigned short*)Cv)[(size_t)row * ldc + cn] = f2bf(v);
                else          ((float*)Cv)[(size_t)row * ldc + cn] = v;
            }
        }
    }
}

// ---------- merged modality GEMMs: z=0 -> f1 (K=2048), z=1 -> f2 (K=768) ----------
__global__ __launch_bounds__(256, 3)
void gemm_f12(const unsigned short* __restrict__ f1b, const unsigned short* __restrict__ W1t,
              const float* __restrict__ b1,
              const unsigned short* __restrict__ f2b, const unsigned short* __restrict__ W2t,
              const float* __restrict__ b2, unsigned short* __restrict__ xb) {
    __shared__ alignas(16) unsigned short As[8192];
    __shared__ alignas(16) unsigned short Bs[8192];
    if (blockIdx.z == 0)
        gemm_core<true, true>(f1b, W1t, (void*)xb, b1, 2048, 2048, As, Bs);
    else
        gemm_core<true, true>(f2b, W2t, (void*)(xb + 1024), b2, 768, 2048, As, Bs);
}

// ---------- out-proj GEMM ----------
__global__ __launch_bounds__(256, 3)
void gemm_proj(const unsigned short* __restrict__ attn, const unsigned short* __restrict__ Woutt,
               const float* __restrict__ bout, unsigned short* __restrict__ projb) {
    __shared__ alignas(16) unsigned short As[8192];
    __shared__ alignas(16) unsigned short Bs[8192];
    gemm_core<true, true>(attn, Woutt, (void*)projb, bout, 1024, 1024, As, Bs);
}

// ---------- fused qkv GEMM + 2x2 attention ----------
// Block = (head h, M-tile of 128 rows = 64 batch entries). Tile N=192 = q|k|v 64-col slices.
#define T2_STRIDE 132
__global__ __launch_bounds__(256, 3)
void gemm_qkv_attn(const unsigned short* __restrict__ A, const unsigned short* __restrict__ Bt,
                   unsigned short* __restrict__ attn_out) {
    __shared__ alignas(16) char smem[52224];
    unsigned short* As = (unsigned short*)smem;        // 8192 elems: 2 halves x [128][32]
    unsigned short* Bs = As + 8192;                    // 12288 elems: 2 halves x [192][32]
    unsigned short* T2 = (unsigned short*)smem;        // 192*132 elems, reuses staging
    float* wsm = (float*)(smem + 50688);               // 64*4 softmax weights

    const int tid  = threadIdx.x;
    const int lane = tid & 63;
    const int wave = tid >> 6;
    const int h = blockIdx.x;                 // head 0..15
    const int blockM = blockIdx.y * 128;
    const int wm = wave >> 1, wn = wave & 1;  // wave tile 64x96
    const int K = 1024;

    const unsigned short* gA = A  + (size_t)(blockM + (tid >> 2)) * K + (tid & 3) * 8;
    const unsigned short* gB = Bt + (size_t)(h * 64 + (tid >> 2)) * K + (tid & 3) * 8;
    unsigned short* lA = As + wave * 512;
    unsigned short* lB = Bs + wave * 512;

    floatx4 acc[4][6];
#pragma unroll
    for (int i = 0; i < 4; i++)
#pragma unroll
        for (int j = 0; j < 6; j++) acc[i][j] = (floatx4){0.f, 0.f, 0.f, 0.f};

    const int col  = lane & 15;
    const int quad = lane >> 4;
    const int aoff32 = (wm * 64 + col) * 32 + quad * 8;
    const int boff32 = (wn * 96 + col) * 32 + quad * 8;

    for (int kt = 0; kt < 16; ++kt) {
        const size_t ko = (size_t)kt * 64;
        gld_lds16(gA + ko,               lA);          // A half0 rows 0..63
        gld_lds16(gA + 65536 + ko,       lA + 2048);   // A half0 rows 64..127
        gld_lds16(gA + 32 + ko,          lA + 4096);   // A half1 rows 0..63
        gld_lds16(gA + 65536 + 32 + ko,  lA + 6144);   // A half1 rows 64..127
        gld_lds16(gB + ko,               lB);          // q, half0
        gld_lds16(gB + 1048576 + ko,     lB + 2048);   // k, half0
        gld_lds16(gB + 2097152 + ko,     lB + 4096);   // v, half0
        gld_lds16(gB + 32 + ko,          lB + 6144);   // q, half1
        gld_lds16(gB + 1048576 + 32 + ko, lB + 8192);  // k, half1
        gld_lds16(gB + 2097152 + 32 + ko, lB + 10240); // v, half1
        __syncthreads();

#pragma unroll
        for (int hh = 0; hh < 2; hh++) {
            short8 a[4];
#pragma unroll
            for (int i = 0; i < 4; i++) a[i] = *(const short8*)&As[hh * 4096 + aoff32 + i * 512];
#pragma unroll
            for (int j = 0; j < 6; j++) {
                short8 bj = *(const short8*)&Bs[hh * 6144 + boff32 + j * 512];
#pragma unroll
                for (int i = 0; i < 4; i++)
                    acc[i][j] = __builtin_amdgcn_mfma_f32_16x16x32_bf16(a[i], bj, acc[i][j], 0, 0, 0);
            }
        }
        __syncthreads();
    }

    // 1) store tile transposed: T2[c][r], c = feature (q|k|v), r = M-row
#pragma unroll
    for (int i = 0; i < 4; i++) {
#pragma unroll
        for (int j = 0; j < 6; j++) {
            int c  = wn * 96 + j * 16 + col;
            int r0 = wm * 64 + i * 16 + quad * 4;
            short4v pk;
            pk.x = (short)f2bf(acc[i][j][0]);
            pk.y = (short)f2bf(acc[i][j][1]);
            pk.z = (short)f2bf(acc[i][j][2]);
            pk.w = (short)f2bf(acc[i][j][3]);
            *(short4v*)&T2[c * T2_STRIDE + r0] = pk;
        }
    }
    __syncthreads();

    // 2) scores + softmax: thread ib (<64) handles batch-row pair (2ib, 2ib+1)
    if (tid < 64) {
        const int ib = tid;
        float s00 = 0.f, s01 = 0.f, s10 = 0.f, s11 = 0.f;
#pragma unroll 8
        for (int d = 0; d < 64; d++) {
            unsigned int qp = *(const unsigned int*)&T2[d * T2_STRIDE + 2 * ib];
            unsigned int kp = *(const unsigned int*)&T2[(64 + d) * T2_STRIDE + 2 * ib];
            float q0 = lo_bf(qp), q1 = hi_bf(qp);
            float k0 = lo_bf(kp), k1 = hi_bf(kp);
            s00 += q0 * k0; s01 += q0 * k1;
            s10 += q1 * k0; s11 += q1 * k1;
        }
        const float sc = 0.125f;   // (1024/16)^-0.5
        s00 *= sc; s01 *= sc; s10 *= sc; s11 *= sc;
        float m0 = fmaxf(s00, s01), m1 = fmaxf(s10, s11);
        float e00 = __expf(s00 - m0), e01 = __expf(s01 - m0);
        float e10 = __expf(s10 - m1), e11 = __expf(s11 - m1);
        float i0 = 1.f / (e00 + e01), i1 = 1.f / (e10 + e11);
        wsm[ib * 4 + 0] = e00 * i0; wsm[ib * 4 + 1] = e01 * i0;
        wsm[ib * 4 + 2] = e10 * i1; wsm[ib * 4 + 3] = e11 * i1;
    }
    __syncthreads();

    // 3) out = attn @ v, write global (128 rows x 64 cols = 1024 8-elem chunks)
#pragma unroll
    for (int g = 0; g < 4; g++) {
        int chunk = g * 256 + tid;
        int r = chunk >> 3;
        int dc = (chunk & 7) * 8;
        int ib = r >> 1, n = r & 1;
        float w0 = wsm[ib * 4 + n * 2 + 0];
        float w1 = wsm[ib * 4 + n * 2 + 1];
        short8 o;
#pragma unroll
        for (int dd = 0; dd < 8; dd++) {
            unsigned int vp = *(const unsigned int*)&T2[(128 + dc + dd) * T2_STRIDE + 2 * ib];
            o[dd] = (short)f2bf(w0 * lo_bf(vp) + w1 * hi_bf(vp));
        }
        *(short8*)&attn_out[(size_t)(blockM + r) * 1024 + h * 64 + dc] = o;
    }
}

// ---------- LayerNorm(2048) + residual ----------
__global__ __launch_bounds__(256) void ln_res_kernel(const unsigned short* __restrict__ proj,
                                                     const unsigned short* __restrict__ xres,
                                                     const float* __restrict__ gamma,
                                                     const float* __restrict__ beta,
                                                     float* __restrict__ out) {
    const int b = blockIdx.x;
    const int tid = threadIdx.x;
    const size_t base = (size_t)b * 2048;
    short8 p8 = ((const short8*)(proj + base))[tid];
    float pv[8];
#pragma unroll
    for (int e = 0; e < 8; e++) pv[e] = bf2f((unsigned short)p8[e]);
    float s = 0.f, ss = 0.f;
#pragma unroll
    for (int e = 0; e < 8; e++) { s += pv[e]; ss += pv[e] * pv[e]; }
#pragma unroll
    for (int off = 32; off > 0; off >>= 1) {
        s  += __shfl_xor(s, off);
        ss += __shfl_xor(ss, off);
    }
    __shared__ float red[8];
    const int wave = tid >> 6;
    if ((tid & 63) == 0) { red[wave] = s; red[4 + wave] = ss; }
    __syncthreads();
    s  = red[0] + red[1] + red[2] + red[3];
    ss = red[4] + red[5] + red[6] + red[7];
    const float mean = s * (1.0f / 2048.0f);
    const float var  = ss * (1.0f / 2048.0f) - mean * mean;
    const float rstd = rsqrtf(var + 1e-5f);

    const float4* g4 = (const float4*)gamma;
    const float4* b4 = (const float4*)beta;
    float4 g0 = g4[2 * tid], g1 = g4[2 * tid + 1];
    float4 be0 = b4[2 * tid], be1 = b4[2 * tid + 1];
    short8 r8 = ((const short8*)(xres + base))[tid];
    float4 o0, o1;
    o0.x = (pv[0] - mean) * rstd * g0.x + be0.x + bf2f((unsigned short)r8[0]);
    o0.y = (pv[1] - mean) * rstd * g0.y + be0.y + bf2f((unsigned short)r8[1]);
    o0.z = (pv[2] - mean) * rstd * g0.z + be0.z + bf2f((unsigned short)r8[2]);
    o0.w = (pv[3] - mean) * rstd * g0.w + be0.w + bf2f((unsigned short)r8[3]);
    o1.x = (pv[4] - mean) * rstd * g1.x + be1.x + bf2f((unsigned short)r8[4]);
    o1.y = (pv[5] - mean) * rstd * g1.y + be1.y + bf2f((unsigned short)r8[5]);
    o1.z = (pv[6] - mean) * rstd * g1.z + be1.z + bf2f((unsigned short)r8[6]);
    o1.w = (pv[7] - mean) * rstd * g1.w + be1.w + bf2f((unsigned short)r8[7]);
    float4* op = (float4*)(out + base);
    op[2 * tid] = o0;
    op[2 * tid + 1] = o1;
}

// ---------- launch ----------
extern "C" void kernel_launch(void* const* d_in, const int* in_sizes, int n_in,
                              void* d_out, int out_size, void* d_ws, size_t ws_size,
                              hipStream_t stream) {
    (void)in_sizes; (void)n_in; (void)out_size; (void)ws_size;
    const float* features1 = (const float*)d_in[0];
    const float* features2 = (const float*)d_in[1];
    const float* W1   = (const float*)d_in[2];
    const float* b1   = (const float*)d_in[3];
    const float* W2   = (const float*)d_in[4];
    const float* b2   = (const float*)d_in[5];
    const float* Wqkv = (const float*)d_in[6];
    const float* Wout = (const float*)d_in[7];
    const float* bout = (const float*)d_in[8];
    const float* gamma = (const float*)d_in[9];
    const float* beta  = (const float*)d_in[10];
    float* out = (float*)d_out;

    // B=8192, IMG=2048, Q=768, H=1024
    char* ws = (char*)d_ws;
    unsigned short* f1b   = (unsigned short*)(ws);                 // 32 MiB
    unsigned short* f2b   = (unsigned short*)(ws + 33554432);      // 12 MiB
    unsigned short* W1t   = (unsigned short*)(ws + 46137344);      // 4 MiB   [1024][2048]
    unsigned short* W2t   = (unsigned short*)(ws + 50331648);      // 1.5 MiB [1024][768]
    unsigned short* Wqkvt = (unsigned short*)(ws + 51904512);      // 6 MiB   [3072][1024]
    unsigned short* Woutt = (unsigned short*)(ws + 58195968);      // 2 MiB   [1024][1024]
    unsigned short* xb    = (unsigned short*)(ws + 60293120);      // 32 MiB  [16384][1024]
    unsigned short* attn  = (unsigned short*)(ws + 93847552);      // 32 MiB  [16384][1024]
    unsigned short* projb = (unsigned short*)(ws + 127401984);     // 32 MiB  [16384][1024] bf16

    // 1) unified prep (feature cvt + weight transposes)
    prep_kernel<<<12544, 256, 0, stream>>>(features1, features2, f1b, f2b,
                                           W1, W1t, W2, W2t, Wqkv, Wqkvt, Wout, Woutt);
    // 2) f1/f2 modality GEMMs, one dispatch
    gemm_f12<<<dim3(8, 64, 2), 256, 0, stream>>>(f1b, W1t, b1, f2b, W2t, b2, xb);
    // 3) fused qkv GEMM + attention -> attn [16384][1024] bf16
    gemm_qkv_attn<<<dim3(16, 128), 256, 0, stream>>>(xb, Wqkvt, attn);
    // 4) proj = attn @ Wout + bout -> bf16
    gemm_proj<<<dim3(8, 128), 256, 0, stream>>>(attn, Woutt, bout, projb);
    // 5) LayerNorm + residual
    ln_res_kernel<<<8192, 256, 0, stream>>>(projb, xb, gamma, beta, out);
}

// Round 5
// 372.818 us; speedup vs baseline: 1.2845x; 1.0668x over previous
//
#include <hip/hip_runtime.h>
#include <hip/hip_bf16.h>
#include <cstdint>

// ---------- types ----------
typedef __attribute__((ext_vector_type(8))) short short8;     // 8 x bf16 raw
typedef __attribute__((ext_vector_type(4))) short short4v;    // 4 x bf16 raw
typedef __attribute__((ext_vector_type(4))) float floatx4;
typedef __attribute__((ext_vector_type(4))) unsigned short ushort4v;

// ---------- helpers ----------
__device__ __forceinline__ float bf2f(unsigned short u) {
    union { unsigned int u; float f; } v;
    v.u = ((unsigned int)u) << 16;
    return v.f;
}
__device__ __forceinline__ unsigned short f2bf(float f) {
    union { float f; unsigned int u; } v; v.f = f;
    unsigned int u = v.u;
    unsigned int r = (u + 0x7FFFu + ((u >> 16) & 1u)) >> 16;  // RNE
    return (unsigned short)r;
}
__device__ __forceinline__ float lo_bf(unsigned int u) {
    union { unsigned int u; float f; } v; v.u = u << 16; return v.f;
}
__device__ __forceinline__ float hi_bf(unsigned int u) {
    union { unsigned int u; float f; } v; v.u = u & 0xffff0000u; return v.f;
}
__device__ __forceinline__ void gld_lds16(const void* g, void* l) {
    __builtin_amdgcn_global_load_lds(
        (const __attribute__((address_space(1))) unsigned int*)g,
        (__attribute__((address_space(3))) unsigned int*)l,
        16, 0, 0);
}

// ---------- unified prep: feature cvt + all weight transposes, ONE dispatch ----------
// blocks [0,4096)      : cvt features1 (4096*1024 float4)
// blocks [4096,5632)   : cvt features2 (1536*1024 float4)
// blocks [5632,6656)   : transpose W1   [2048][1024] (64k x 32n tiles -> 1024)
// blocks [6656,7040)   : transpose W2   [768][1024]  (384 tiles)
// blocks [7040,8576)   : transpose Wqkv [1024][3072] (1536 tiles)
// blocks [8576,9088)   : transpose Wout [1024][1024] (512 tiles)
__global__ __launch_bounds__(256) void prep_kernel(
    const float* __restrict__ f1, const float* __restrict__ f2,
    unsigned short* __restrict__ f1b, unsigned short* __restrict__ f2b,
    const float* __restrict__ W1, unsigned short* __restrict__ W1t,
    const float* __restrict__ W2, unsigned short* __restrict__ W2t,
    const float* __restrict__ Wqkv, unsigned short* __restrict__ Wqkvt,
    const float* __restrict__ Wout, unsigned short* __restrict__ Woutt) {
    __shared__ float tile[64][33];
    const int b = blockIdx.x;
    const int tid = threadIdx.x;

    if (b < 5632) {
        const float* in = (b < 4096) ? f1 : f2;
        unsigned short* outp = (b < 4096) ? f1b : f2b;
        int base = ((b < 4096) ? b : (b - 4096)) * 1024 + tid;
#pragma unroll
        for (int it = 0; it < 4; it++) {
            int i = base + it * 256;
            float4 v = ((const float4*)in)[i];
            ushort4v o;
            o.x = f2bf(v.x); o.y = f2bf(v.y); o.z = f2bf(v.z); o.w = f2bf(v.w);
            ((ushort4v*)outp)[i] = o;
        }
        return;
    }

    // transpose: 64 k-rows x 32 n-cols per tile; write short8 (16B) along K
    const float* in; unsigned short* outp; int K, N, t;
    if (b < 6656)      { in = W1;   outp = W1t;   K = 2048; N = 1024; t = b - 5632; }
    else if (b < 7040) { in = W2;   outp = W2t;   K = 768;  N = 1024; t = b - 6656; }
    else if (b < 8576) { in = Wqkv; outp = Wqkvt; K = 1024; N = 3072; t = b - 7040; }
    else               { in = Wout; outp = Woutt; K = 1024; N = 1024; t = b - 8576; }
    const int ntiles = N >> 5;
    const int n0 = (t % ntiles) * 32;
    const int k0 = (t / ntiles) * 64;
    const int tx = tid & 31, tg = tid >> 5;   // tg 0..7
#pragma unroll
    for (int i = 0; i < 8; i++)
        tile[tg * 8 + i][tx] = in[(size_t)(k0 + tg * 8 + i) * N + n0 + tx];
    __syncthreads();
    const int n = tid >> 3, kc = (tid & 7) * 8;
    short8 o;
#pragma unroll
    for (int j = 0; j < 8; j++) o[j] = (short)f2bf(tile[kc + j][n]);
    *(short8*)&outp[(size_t)(n0 + n) * K + k0 + kc] = o;
}

// ---------- bf16 GEMM core, BK=64: C[M][N] = A[M][K]*Bt[N][K]^T (+bias) ----------
template <bool OUT_BF16, bool HAS_BIAS>
__device__ __forceinline__ void gemm_core(const unsigned short* __restrict__ A,
                                          const unsigned short* __restrict__ Bt,
                                          void* __restrict__ Cv, const float* __restrict__ bias,
                                          int K, int ldc, int blockM, int blockN,
                                          unsigned short* As, unsigned short* Bs) {
    const int tid  = threadIdx.x;
    const int lane = tid & 63;
    const int wave = tid >> 6;
    const int wm = wave >> 1, wn = wave & 1;

    const unsigned short* gA = A  + (size_t)(blockM + (tid >> 2)) * K + (tid & 3) * 8;
    const unsigned short* gB = Bt + (size_t)(blockN + (tid >> 2)) * K + (tid & 3) * 8;
    const size_t sK = (size_t)64 * K;          // +64 rows
    unsigned short* lA = As + wave * 512;      // wave-uniform; lane*16B implicit
    unsigned short* lB = Bs + wave * 512;

    floatx4 acc[4][4];
#pragma unroll
    for (int i = 0; i < 4; i++)
#pragma unroll
        for (int j = 0; j < 4; j++) acc[i][j] = (floatx4){0.f, 0.f, 0.f, 0.f};

    const int col  = lane & 15;
    const int quad = lane >> 4;
    const int aoff32 = (wm * 64 + col) * 32 + quad * 8;
    const int boff32 = (wn * 64 + col) * 32 + quad * 8;

    const int kIters = K >> 6;
    for (int kt = 0; kt < kIters; ++kt) {
        const size_t ko = (size_t)kt * 64;
        gld_lds16(gA + ko,           lA);
        gld_lds16(gA + sK + ko,      lA + 2048);
        gld_lds16(gA + 32 + ko,      lA + 4096);
        gld_lds16(gA + sK + 32 + ko, lA + 6144);
        gld_lds16(gB + ko,           lB);
        gld_lds16(gB + sK + ko,      lB + 2048);
        gld_lds16(gB + 32 + ko,      lB + 4096);
        gld_lds16(gB + sK + 32 + ko, lB + 6144);
        __syncthreads();

#pragma unroll
        for (int hh = 0; hh < 2; hh++) {
            short8 a[4];
#pragma unroll
            for (int i = 0; i < 4; i++) a[i] = *(const short8*)&As[hh * 4096 + aoff32 + i * 512];
#pragma unroll
            for (int j = 0; j < 4; j++) {
                short8 bj = *(const short8*)&Bs[hh * 4096 + boff32 + j * 512];
#pragma unroll
                for (int i = 0; i < 4; i++)
                    acc[i][j] = __builtin_amdgcn_mfma_f32_16x16x32_bf16(a[i], bj, acc[i][j], 0, 0, 0);
            }
        }
        __syncthreads();
    }

    // epilogue: C/D layout col=lane&15, row=quad*4+reg
#pragma unroll
    for (int i = 0; i < 4; i++) {
#pragma unroll
        for (int j = 0; j < 4; j++) {
#pragma unroll
            for (int r = 0; r < 4; r++) {
                int row = blockM + wm * 64 + i * 16 + quad * 4 + r;
                int cn  = blockN + wn * 64 + j * 16 + col;
                float v = acc[i][j][r];
                if (HAS_BIAS) v += bias[cn];
                if (OUT_BF16) ((unsigned short*)Cv)[(size_t)row * ldc + cn] = f2bf(v);
                else          ((float*)Cv)[(size_t)row * ldc + cn] = v;
            }
        }
    }
}

// ---------- merged modality GEMMs: x = M-tile (fast => same-XCD A sharing), y = N-tile ----------
__global__ __launch_bounds__(256, 3)
void gemm_f12(const unsigned short* __restrict__ f1b, const unsigned short* __restrict__ W1t,
              const float* __restrict__ b1,
              const unsigned short* __restrict__ f2b, const unsigned short* __restrict__ W2t,
              const float* __restrict__ b2, unsigned short* __restrict__ xb) {
    __shared__ alignas(16) unsigned short As[8192];
    __shared__ alignas(16) unsigned short Bs[8192];
    const int blockM = blockIdx.x * 128;   // M fastest: blocks sharing B-weights run consecutively;
    const int blockN = blockIdx.y * 128;   // blocks sharing A differ only in y => same XCD (x mod 8 fixed)
    if (blockIdx.z == 0)
        gemm_core<true, true>(f1b, W1t, (void*)xb, b1, 2048, 2048, blockM, blockN, As, Bs);
    else
        gemm_core<true, true>(f2b, W2t, (void*)(xb + 1024), b2, 768, 2048, blockM, blockN, As, Bs);
}

// ---------- out-proj GEMM ----------
__global__ __launch_bounds__(256, 3)
void gemm_proj(const unsigned short* __restrict__ attn, const unsigned short* __restrict__ Woutt,
               const float* __restrict__ bout, unsigned short* __restrict__ projb) {
    __shared__ alignas(16) unsigned short As[8192];
    __shared__ alignas(16) unsigned short Bs[8192];
    gemm_core<true, true>(attn, Woutt, (void*)projb, bout, 1024, 1024,
                          blockIdx.x * 128, blockIdx.y * 128, As, Bs);
}

// ---------- fused qkv GEMM + 2x2 attention ----------
// Flat grid 2048: m = g&127 (fast => 16 head-blocks of tile m share XCD), h = g>>7.
#define T2_STRIDE 132
__global__ __launch_bounds__(256, 3)
void gemm_qkv_attn(const unsigned short* __restrict__ A, const unsigned short* __restrict__ Bt,
                   unsigned short* __restrict__ attn_out) {
    __shared__ alignas(16) char smem[52224];
    unsigned short* As = (unsigned short*)smem;        // 8192 elems: 2 halves x [128][32]
    unsigned short* Bs = As + 8192;                    // 12288 elems: 2 halves x [192][32]
    unsigned short* T2 = (unsigned short*)smem;        // 192*132 elems, reuses staging
    float* wsm = (float*)(smem + 50688);               // 64*4 softmax weights

    const int tid  = threadIdx.x;
    const int lane = tid & 63;
    const int wave = tid >> 6;
    const int g = blockIdx.x;
    const int h = g >> 7;                     // head 0..15
    const int blockM = (g & 127) * 128;       // M-tile fastest => same-XCD A sharing
    const int wm = wave >> 1, wn = wave & 1;  // wave tile 64x96
    const int K = 1024;

    const unsigned short* gA = A  + (size_t)(blockM + (tid >> 2)) * K + (tid & 3) * 8;
    const unsigned short* gB = Bt + (size_t)(h * 64 + (tid >> 2)) * K + (tid & 3) * 8;
    unsigned short* lA = As + wave * 512;
    unsigned short* lB = Bs + wave * 512;

    floatx4 acc[4][6];
#pragma unroll
    for (int i = 0; i < 4; i++)
#pragma unroll
        for (int j = 0; j < 6; j++) acc[i][j] = (floatx4){0.f, 0.f, 0.f, 0.f};

    const int col  = lane & 15;
    const int quad = lane >> 4;
    const int aoff32 = (wm * 64 + col) * 32 + quad * 8;
    const int boff32 = (wn * 96 + col) * 32 + quad * 8;

    for (int kt = 0; kt < 16; ++kt) {
        const size_t ko = (size_t)kt * 64;
        gld_lds16(gA + ko,               lA);          // A half0 rows 0..63
        gld_lds16(gA + 65536 + ko,       lA + 2048);   // A half0 rows 64..127
        gld_lds16(gA + 32 + ko,          lA + 4096);   // A half1 rows 0..63
        gld_lds16(gA + 65536 + 32 + ko,  lA + 6144);   // A half1 rows 64..127
        gld_lds16(gB + ko,               lB);          // q, half0
        gld_lds16(gB + 1048576 + ko,     lB + 2048);   // k, half0
        gld_lds16(gB + 2097152 + ko,     lB + 4096);   // v, half0
        gld_lds16(gB + 32 + ko,          lB + 6144);   // q, half1
        gld_lds16(gB + 1048576 + 32 + ko, lB + 8192);  // k, half1
        gld_lds16(gB + 2097152 + 32 + ko, lB + 10240); // v, half1
        __syncthreads();

#pragma unroll
        for (int hh = 0; hh < 2; hh++) {
            short8 a[4];
#pragma unroll
            for (int i = 0; i < 4; i++) a[i] = *(const short8*)&As[hh * 4096 + aoff32 + i * 512];
#pragma unroll
            for (int j = 0; j < 6; j++) {
                short8 bj = *(const short8*)&Bs[hh * 6144 + boff32 + j * 512];
#pragma unroll
                for (int i = 0; i < 4; i++)
                    acc[i][j] = __builtin_amdgcn_mfma_f32_16x16x32_bf16(a[i], bj, acc[i][j], 0, 0, 0);
            }
        }
        __syncthreads();
    }

    // 1) store tile transposed: T2[c][r], c = feature (q|k|v), r = M-row
#pragma unroll
    for (int i = 0; i < 4; i++) {
#pragma unroll
        for (int j = 0; j < 6; j++) {
            int c  = wn * 96 + j * 16 + col;
            int r0 = wm * 64 + i * 16 + quad * 4;
            short4v pk;
            pk.x = (short)f2bf(acc[i][j][0]);
            pk.y = (short)f2bf(acc[i][j][1]);
            pk.z = (short)f2bf(acc[i][j][2]);
            pk.w = (short)f2bf(acc[i][j][3]);
            *(short4v*)&T2[c * T2_STRIDE + r0] = pk;
        }
    }
    __syncthreads();

    // 2) scores + softmax: thread ib (<64) handles batch-row pair (2ib, 2ib+1)
    if (tid < 64) {
        const int ib = tid;
        float s00 = 0.f, s01 = 0.f, s10 = 0.f, s11 = 0.f;
#pragma unroll 8
        for (int d = 0; d < 64; d++) {
            unsigned int qp = *(const unsigned int*)&T2[d * T2_STRIDE + 2 * ib];
            unsigned int kp = *(const unsigned int*)&T2[(64 + d) * T2_STRIDE + 2 * ib];
            float q0 = lo_bf(qp), q1 = hi_bf(qp);
            float k0 = lo_bf(kp), k1 = hi_bf(kp);
            s00 += q0 * k0; s01 += q0 * k1;
            s10 += q1 * k0; s11 += q1 * k1;
        }
        const float sc = 0.125f;   // (1024/16)^-0.5
        s00 *= sc; s01 *= sc; s10 *= sc; s11 *= sc;
        float m0 = fmaxf(s00, s01), m1 = fmaxf(s10, s11);
        float e00 = __expf(s00 - m0), e01 = __expf(s01 - m0);
        float e10 = __expf(s10 - m1), e11 = __expf(s11 - m1);
        float i0 = 1.f / (e00 + e01), i1 = 1.f / (e10 + e11);
        wsm[ib * 4 + 0] = e00 * i0; wsm[ib * 4 + 1] = e01 * i0;
        wsm[ib * 4 + 2] = e10 * i1; wsm[ib * 4 + 3] = e11 * i1;
    }
    __syncthreads();

    // 3) out = attn @ v, write global (128 rows x 64 cols = 1024 8-elem chunks)
#pragma unroll
    for (int gg = 0; gg < 4; gg++) {
        int chunk = gg * 256 + tid;
        int r = chunk >> 3;
        int dc = (chunk & 7) * 8;
        int ib = r >> 1, n = r & 1;
        float w0 = wsm[ib * 4 + n * 2 + 0];
        float w1 = wsm[ib * 4 + n * 2 + 1];
        short8 o;
#pragma unroll
        for (int dd = 0; dd < 8; dd++) {
            unsigned int vp = *(const unsigned int*)&T2[(128 + dc + dd) * T2_STRIDE + 2 * ib];
            o[dd] = (short)f2bf(w0 * lo_bf(vp) + w1 * hi_bf(vp));
        }
        *(short8*)&attn_out[(size_t)(blockM + r) * 1024 + h * 64 + dc] = o;
    }
}

// ---------- LayerNorm(2048) + residual ----------
__global__ __launch_bounds__(256) void ln_res_kernel(const unsigned short* __restrict__ proj,
                                                     const unsigned short* __restrict__ xres,
                                                     const float* __restrict__ gamma,
                                                     const float* __restrict__ beta,
                                                     float* __restrict__ out) {
    const int b = blockIdx.x;
    const int tid = threadIdx.x;
    const size_t base = (size_t)b * 2048;
    short8 p8 = ((const short8*)(proj + base))[tid];
    float pv[8];
#pragma unroll
    for (int e = 0; e < 8; e++) pv[e] = bf2f((unsigned short)p8[e]);
    float s = 0.f, ss = 0.f;
#pragma unroll
    for (int e = 0; e < 8; e++) { s += pv[e]; ss += pv[e] * pv[e]; }
#pragma unroll
    for (int off = 32; off > 0; off >>= 1) {
        s  += __shfl_xor(s, off);
        ss += __shfl_xor(ss, off);
    }
    __shared__ float red[8];
    const int wave = tid >> 6;
    if ((tid & 63) == 0) { red[wave] = s; red[4 + wave] = ss; }
    __syncthreads();
    s  = red[0] + red[1] + red[2] + red[3];
    ss = red[4] + red[5] + red[6] + red[7];
    const float mean = s * (1.0f / 2048.0f);
    const float var  = ss * (1.0f / 2048.0f) - mean * mean;
    const float rstd = rsqrtf(var + 1e-5f);

    const float4* g4 = (const float4*)gamma;
    const float4* b4 = (const float4*)beta;
    float4 g0 = g4[2 * tid], g1 = g4[2 * tid + 1];
    float4 be0 = b4[2 * tid], be1 = b4[2 * tid + 1];
    short8 r8 = ((const short8*)(xres + base))[tid];
    float4 o0, o1;
    o0.x = (pv[0] - mean) * rstd * g0.x + be0.x + bf2f((unsigned short)r8[0]);
    o0.y = (pv[1] - mean) * rstd * g0.y + be0.y + bf2f((unsigned short)r8[1]);
    o0.z = (pv[2] - mean) * rstd * g0.z + be0.z + bf2f((unsigned short)r8[2]);
    o0.w = (pv[3] - mean) * rstd * g0.w + be0.w + bf2f((unsigned short)r8[3]);
    o1.x = (pv[4] - mean) * rstd * g1.x + be1.x + bf2f((unsigned short)r8[4]);
    o1.y = (pv[5] - mean) * rstd * g1.y + be1.y + bf2f((unsigned short)r8[5]);
    o1.z = (pv[6] - mean) * rstd * g1.z + be1.z + bf2f((unsigned short)r8[6]);
    o1.w = (pv[7] - mean) * rstd * g1.w + be1.w + bf2f((unsigned short)r8[7]);
    float4* op = (float4*)(out + base);
    op[2 * tid] = o0;
    op[2 * tid + 1] = o1;
}

// ---------- launch ----------
extern "C" void kernel_launch(void* const* d_in, const int* in_sizes, int n_in,
                              void* d_out, int out_size, void* d_ws, size_t ws_size,
                              hipStream_t stream) {
    (void)in_sizes; (void)n_in; (void)out_size; (void)ws_size;
    const float* features1 = (const float*)d_in[0];
    const float* features2 = (const float*)d_in[1];
    const float* W1   = (const float*)d_in[2];
    const float* b1   = (const float*)d_in[3];
    const float* W2   = (const float*)d_in[4];
    const float* b2   = (const float*)d_in[5];
    const float* Wqkv = (const float*)d_in[6];
    const float* Wout = (const float*)d_in[7];
    const float* bout = (const float*)d_in[8];
    const float* gamma = (const float*)d_in[9];
    const float* beta  = (const float*)d_in[10];
    float* out = (float*)d_out;

    // B=8192, IMG=2048, Q=768, H=1024
    char* ws = (char*)d_ws;
    unsigned short* f1b   = (unsigned short*)(ws);                 // 32 MiB
    unsigned short* f2b   = (unsigned short*)(ws + 33554432);      // 12 MiB
    unsigned short* W1t   = (unsigned short*)(ws + 46137344);      // 4 MiB   [1024][2048]
    unsigned short* W2t   = (unsigned short*)(ws + 50331648);      // 1.5 MiB [1024][768]
    unsigned short* Wqkvt = (unsigned short*)(ws + 51904512);      // 6 MiB   [3072][1024]
    unsigned short* Woutt = (unsigned short*)(ws + 58195968);      // 2 MiB   [1024][1024]
    unsigned short* xb    = (unsigned short*)(ws + 60293120);      // 32 MiB  [16384][1024]
    unsigned short* attn  = (unsigned short*)(ws + 93847552);      // 32 MiB  [16384][1024]
    unsigned short* projb = (unsigned short*)(ws + 127401984);     // 32 MiB  [16384][1024] bf16

    // 1) unified prep (feature cvt + weight transposes)
    prep_kernel<<<9088, 256, 0, stream>>>(features1, features2, f1b, f2b,
                                          W1, W1t, W2, W2t, Wqkv, Wqkvt, Wout, Woutt);
    // 2) f1/f2 modality GEMMs (x = M fastest for XCD A-locality)
    gemm_f12<<<dim3(64, 8, 2), 256, 0, stream>>>(f1b, W1t, b1, f2b, W2t, b2, xb);
    // 3) fused qkv GEMM + attention -> attn [16384][1024] bf16
    gemm_qkv_attn<<<2048, 256, 0, stream>>>(xb, Wqkvt, attn);
    // 4) proj = attn @ Wout + bout -> bf16 (x = M fastest)
    gemm_proj<<<dim3(128, 8), 256, 0, stream>>>(attn, Woutt, bout, projb);
    // 5) LayerNorm + residual
    ln_res_kernel<<<8192, 256, 0, stream>>>(projb, xb, gamma, beta, out);
}